// Round 1
// baseline (829.966 us; speedup 1.0000x reference)
//
#include <hip/hip_runtime.h>
#include <hip/hip_bf16.h>
#include <math.h>

// Problem constants
#define LSEQ   4096
#define DIM    768
#define DINNER 1536
#define DSTATE 16
#define NCOLS  4640          // 3*DINNER + 2*DSTATE
#define NCH    64            // scan chunks
#define CLEN   64            // steps per chunk  (NCH*CLEN == LSEQ)

// ---------------------------------------------------------------------------
// Generic fp32 GEMM:  C[M,N] = A[M,K] * B[N,K]^T   (both row-major, K-contig)
// 128x128 block, BK=8, 256 threads, 8x8 per thread.
// ---------------------------------------------------------------------------
#define BM 128
#define BN 128
#define BKK 8

__global__ __launch_bounds__(256) void gemm_nt(const float* __restrict__ A,
                                               const float* __restrict__ B,
                                               float* __restrict__ C,
                                               int M, int N, int K) {
    __shared__ float As[BKK][BM];
    __shared__ float Bs[BKK][BN];
    const int tid = threadIdx.x;
    const int tx = tid & 15;        // 0..15  -> 8 cols each
    const int ty = tid >> 4;        // 0..15  -> 8 rows each
    const int m0 = blockIdx.y * BM;
    const int n0 = blockIdx.x * BN;
    const int lrow = tid >> 1;      // 0..127
    const int lk   = (tid & 1) * 4; // 0 or 4

    float acc[8][8];
#pragma unroll
    for (int i = 0; i < 8; i++)
#pragma unroll
        for (int j = 0; j < 8; j++) acc[i][j] = 0.f;

    for (int k0 = 0; k0 < K; k0 += BKK) {
        float4 av = make_float4(0.f, 0.f, 0.f, 0.f);
        float4 bv = make_float4(0.f, 0.f, 0.f, 0.f);
        const int am = m0 + lrow;
        const int bn = n0 + lrow;
        if (am < M) av = *(const float4*)(A + (size_t)am * K + k0 + lk);
        if (bn < N) bv = *(const float4*)(B + (size_t)bn * K + k0 + lk);
        __syncthreads();   // previous tile fully consumed
        As[lk + 0][lrow] = av.x; As[lk + 1][lrow] = av.y;
        As[lk + 2][lrow] = av.z; As[lk + 3][lrow] = av.w;
        Bs[lk + 0][lrow] = bv.x; Bs[lk + 1][lrow] = bv.y;
        Bs[lk + 2][lrow] = bv.z; Bs[lk + 3][lrow] = bv.w;
        __syncthreads();
#pragma unroll
        for (int k = 0; k < BKK; ++k) {
            float4 a0 = *(const float4*)&As[k][ty * 8];
            float4 a1 = *(const float4*)&As[k][ty * 8 + 4];
            float4 b0 = *(const float4*)&Bs[k][tx * 8];
            float4 b1 = *(const float4*)&Bs[k][tx * 8 + 4];
            float a[8] = {a0.x, a0.y, a0.z, a0.w, a1.x, a1.y, a1.z, a1.w};
            float b[8] = {b0.x, b0.y, b0.z, b0.w, b1.x, b1.y, b1.z, b1.w};
#pragma unroll
            for (int i = 0; i < 8; i++)
#pragma unroll
                for (int j = 0; j < 8; j++)
                    acc[i][j] += a[i] * b[j];
        }
    }
#pragma unroll
    for (int i = 0; i < 8; i++) {
        const int row = m0 + ty * 8 + i;
        if (row >= M) continue;
#pragma unroll
        for (int j = 0; j < 8; j++) {
            const int col = n0 + tx * 8 + j;
            if (col < N) C[(size_t)row * N + col] = acc[i][j];
        }
    }
}

// ---------------------------------------------------------------------------
// prep: depthwise conv(k=3,pad=1)+SiLU -> xc ; softplus(delta) -> dt ;
//       compact B_ssm/C_ssm rows.
// grid (DINNER/256, LSEQ) x 256
// ---------------------------------------------------------------------------
__global__ __launch_bounds__(256) void prep_kernel(const float* __restrict__ xz,
                                                   const float* __restrict__ Wc,
                                                   float* __restrict__ xc,
                                                   float* __restrict__ dt,
                                                   float* __restrict__ Bc,
                                                   float* __restrict__ Cc) {
    const int l = blockIdx.y;
    const int d = blockIdx.x * 256 + threadIdx.x;
    const float* row = xz + (size_t)l * NCOLS;

    float x0 = row[d];
    float xm = (l > 0)        ? xz[(size_t)(l - 1) * NCOLS + d] : 0.f;
    float xp = (l < LSEQ - 1) ? xz[(size_t)(l + 1) * NCOLS + d] : 0.f;
    float w0 = Wc[d * 3 + 0], w1 = Wc[d * 3 + 1], w2 = Wc[d * 3 + 2];
    float v = xm * w0 + x0 * w1 + xp * w2;
    float sv = __fdividef(v, 1.f + __expf(-v));        // silu
    xc[(size_t)l * DINNER + d] = sv;

    float draw = row[3104 + d];
    float dtv = (draw > 20.f) ? draw : log1pf(__expf(draw));   // softplus
    dt[(size_t)l * DINNER + d] = dtv;

    if (blockIdx.x == 0 && threadIdx.x < 32) {
        int t = threadIdx.x;
        if (t < 16) Bc[l * DSTATE + t]        = row[3072 + t];
        else        Cc[l * DSTATE + (t - 16)] = row[3088 + (t - 16)];
    }
}

// ---------------------------------------------------------------------------
// scan phase 1: per chunk, local scan from h=0 -> h_end ; decay product
//               aprod = exp(A * sum(dt)).   Layout [(c*16+n)*1536 + d].
// grid (DINNER/256, NCH) x 256
// ---------------------------------------------------------------------------
__global__ __launch_bounds__(256) void scan1_kernel(const float* __restrict__ dt,
                                                    const float* __restrict__ xc,
                                                    const float* __restrict__ Bc,
                                                    const float* __restrict__ A_log,
                                                    float* __restrict__ aprod,
                                                    float* __restrict__ hend) {
    __shared__ float Bs[CLEN * DSTATE];
    const int d  = blockIdx.x * 256 + threadIdx.x;
    const int c  = blockIdx.y;
    const int l0 = c * CLEN;
    for (int i = threadIdx.x; i < CLEN * DSTATE; i += 256)
        Bs[i] = Bc[l0 * DSTATE + i];
    float Areg[DSTATE];
#pragma unroll
    for (int n = 0; n < DSTATE; n++) Areg[n] = -__expf(A_log[d * DSTATE + n]);
    __syncthreads();

    float h[DSTATE];
#pragma unroll
    for (int n = 0; n < DSTATE; n++) h[n] = 0.f;
    float S = 0.f;

    for (int t = 0; t < CLEN; t++) {
        const int l = l0 + t;
        float dtv = dt[(size_t)l * DINNER + d];
        float u   = dtv * xc[(size_t)l * DINNER + d];
        S += dtv;
#pragma unroll
        for (int n = 0; n < DSTATE; n++) {
            float e = __expf(dtv * Areg[n]);
            h[n] = e * h[n] + u * Bs[t * DSTATE + n];
        }
    }
#pragma unroll
    for (int n = 0; n < DSTATE; n++) {
        size_t idx = ((size_t)c * DSTATE + n) * DINNER + d;
        aprod[idx] = __expf(S * Areg[n]);
        hend[idx]  = h[n];
    }
}

// ---------------------------------------------------------------------------
// scan phase 2: sequential over chunk summaries. 24576 threads, one (d,n) each.
// ---------------------------------------------------------------------------
__global__ __launch_bounds__(256) void scan2_kernel(const float* __restrict__ aprod,
                                                    const float* __restrict__ hend,
                                                    float* __restrict__ hinit) {
    const int g = blockIdx.x * 256 + threadIdx.x;   // g = n*1536 + d
    float h = 0.f;
    for (int c = 0; c < NCH; c++) {
        size_t idx = (size_t)c * (DSTATE * DINNER) + g;
        hinit[idx] = h;
        h = aprod[idx] * h + hend[idx];
    }
}

// ---------------------------------------------------------------------------
// scan phase 3: replay chunk from correct h_init, produce
//   yf = (y_scan + xc*D) * silu(z)
// ---------------------------------------------------------------------------
__global__ __launch_bounds__(256) void scan3_kernel(const float* __restrict__ dt,
                                                    const float* __restrict__ xc,
                                                    const float* __restrict__ Bc,
                                                    const float* __restrict__ Cc,
                                                    const float* __restrict__ A_log,
                                                    const float* __restrict__ hinit,
                                                    const float* __restrict__ xz,
                                                    const float* __restrict__ Dp,
                                                    float* __restrict__ yf) {
    __shared__ float Bs[CLEN * DSTATE];
    __shared__ float Cs[CLEN * DSTATE];
    const int d  = blockIdx.x * 256 + threadIdx.x;
    const int c  = blockIdx.y;
    const int l0 = c * CLEN;
    for (int i = threadIdx.x; i < CLEN * DSTATE; i += 256) {
        Bs[i] = Bc[l0 * DSTATE + i];
        Cs[i] = Cc[l0 * DSTATE + i];
    }
    float Areg[DSTATE];
#pragma unroll
    for (int n = 0; n < DSTATE; n++) Areg[n] = -__expf(A_log[d * DSTATE + n]);
    float h[DSTATE];
#pragma unroll
    for (int n = 0; n < DSTATE; n++)
        h[n] = hinit[((size_t)c * DSTATE + n) * DINNER + d];
    const float Dv = Dp[d];
    __syncthreads();

    for (int t = 0; t < CLEN; t++) {
        const int l = l0 + t;
        float dtv = dt[(size_t)l * DINNER + d];
        float xcv = xc[(size_t)l * DINNER + d];
        float u   = dtv * xcv;
        float y   = 0.f;
#pragma unroll
        for (int n = 0; n < DSTATE; n++) {
            float e = __expf(dtv * Areg[n]);
            h[n] = e * h[n] + u * Bs[t * DSTATE + n];
            y += h[n] * Cs[t * DSTATE + n];
        }
        float z  = xz[(size_t)l * NCOLS + DINNER + d];
        float sz = __fdividef(z, 1.f + __expf(-z));   // silu(z)
        yf[(size_t)l * DINNER + d] = (y + xcv * Dv) * sz;
    }
}

// ---------------------------------------------------------------------------
extern "C" void kernel_launch(void* const* d_in, const int* in_sizes, int n_in,
                              void* d_out, int out_size, void* d_ws, size_t ws_size,
                              hipStream_t stream) {
    const float* x     = (const float*)d_in[0];   // [4096, 768]
    const float* W_in  = (const float*)d_in[1];   // [4640, 768]
    const float* W_conv= (const float*)d_in[2];   // [1536, 3]
    const float* W_out = (const float*)d_in[3];   // [768, 1536]
    const float* A_log = (const float*)d_in[4];   // [1536, 16]
    const float* Dp    = (const float*)d_in[5];   // [1536]
    float* out = (float*)d_out;                   // [4096, 768]

    // workspace carve-up (fp32 elements)
    float* ws  = (float*)d_ws;
    float* xz  = ws;                                  // 4096*4640 = 19,005,440
    float* xc  = xz + (size_t)LSEQ * NCOLS;           // 6,291,456
    float* dt  = xc + (size_t)LSEQ * DINNER;          // 6,291,456
    float* Bc  = dt + (size_t)LSEQ * DINNER;          // 65,536
    float* Cc  = Bc + (size_t)LSEQ * DSTATE;          // 65,536
    float* ap  = Cc + (size_t)LSEQ * DSTATE;          // 1,572,864
    float* he  = ap + (size_t)NCH * DSTATE * DINNER;  // 1,572,864
    float* hi  = he + (size_t)NCH * DSTATE * DINNER;  // 1,572,864
    float* yf  = hi + (size_t)NCH * DSTATE * DINNER;  // 6,291,456
    // total ~171 MB

    // 1) xz = x @ W_in^T
    gemm_nt<<<dim3((NCOLS + BN - 1) / BN, LSEQ / BM), 256, 0, stream>>>(
        x, W_in, xz, LSEQ, NCOLS, DIM);
    // 2) conv+silu, softplus, compact B/C
    prep_kernel<<<dim3(DINNER / 256, LSEQ), 256, 0, stream>>>(
        xz, W_conv, xc, dt, Bc, Cc);
    // 3) chunked scan
    scan1_kernel<<<dim3(DINNER / 256, NCH), 256, 0, stream>>>(
        dt, xc, Bc, A_log, ap, he);
    scan2_kernel<<<(DINNER * DSTATE) / 256, 256, 0, stream>>>(ap, he, hi);
    scan3_kernel<<<dim3(DINNER / 256, NCH), 256, 0, stream>>>(
        dt, xc, Bc, Cc, A_log, hi, xz, Dp, yf);
    // 4) out = yf @ W_out^T
    gemm_nt<<<dim3(DIM / BN, LSEQ / BM), 256, 0, stream>>>(
        yf, W_out, out, LSEQ, DIM, DINNER);
}

// Round 2
// 425.746 us; speedup vs baseline: 1.9494x; 1.9494x over previous
//
#include <hip/hip_runtime.h>
#include <hip/hip_bf16.h>
#include <math.h>

// Problem constants
#define LSEQ   4096
#define DIM    768
#define DINNER 1536
#define DSTATE 16
#define NCOLS  4640          // 3*DINNER + 2*DSTATE
#define NCH    64            // scan chunks
#define CLEN   64            // steps per chunk  (NCH*CLEN == LSEQ)

#define NPAD   4736          // W_in rows padded to multiple of 128
#define K1     2304          // 3*768  (split-bf16 K for GEMM1)
#define K2G    4608          // 3*1536 (split-bf16 K for GEMM2)

// ---------------------------------------------------------------------------
// bf16 helpers (round-to-nearest-even) + split hi/lo
// ---------------------------------------------------------------------------
__device__ __forceinline__ unsigned short f2bf(float f) {
    unsigned int u = __float_as_uint(f);
    u += 0x7FFFu + ((u >> 16) & 1u);
    return (unsigned short)(u >> 16);
}
__device__ __forceinline__ float bf2f(unsigned short h) {
    return __uint_as_float(((unsigned int)h) << 16);
}

// async global(16B/lane) -> LDS staging
__device__ __forceinline__ void gld_lds16(void* lds_dst, const void* gsrc) {
    __builtin_amdgcn_global_load_lds(
        (__attribute__((address_space(1))) void*)(gsrc),
        (__attribute__((address_space(3))) void*)(lds_dst), 16, 0, 0);
}

typedef __attribute__((ext_vector_type(8))) short bf16x8;
typedef __attribute__((ext_vector_type(4))) float f32x4;

// ---------------------------------------------------------------------------
// Split-precision bf16 MFMA GEMM:  C[M,N](fp32) = A'[M,K2]*B'[N,K2]^T
// A' = [hi|hi|lo], B' = [hi|lo|hi] along K  => hi*hi + hi*lo + lo*hi.
// 256 threads (4 waves). Wave grid (BM/WM) x (BN/WN) must equal 4 waves.
// LDS tiles stored packed [rows][32 bf16] with 16B-block XOR swizzle
// (block' = block ^ (row&3)) applied on the global_load_lds side.
// ---------------------------------------------------------------------------
template<int BM, int BN, int WM, int WN>
__global__ __launch_bounds__(256) void gemm_bf16_nt(const short* __restrict__ A,
                                                    const short* __restrict__ B,
                                                    float* __restrict__ C,
                                                    int M, int N, int K2, int ldc) {
    constexpr int MI  = WM / 16;
    constexpr int NI  = WN / 16;
    constexpr int NWN = BN / WN;              // waves along n
    constexpr int NT  = (BM + BN) / 16;       // staging instructions per k-step

    __shared__ __align__(16) short As[BM * 32];
    __shared__ __align__(16) short Bs[BN * 32];

    const int tid  = threadIdx.x;
    const int w    = tid >> 6;
    const int lane = tid & 63;
    const int wr   = w / NWN;
    const int wc   = w % NWN;
    const int m0   = blockIdx.y * BM;
    const int n0   = blockIdx.x * BN;
    const int m    = lane & 15;               // fragment row (A) / col (B)
    const int q    = lane >> 4;               // quad
    const int rsub = lane >> 2;               // staging: row within 16-row group
    const int bsel = lane & 3;                // staging: 16B block index

    f32x4 acc[MI][NI];
#pragma unroll
    for (int i = 0; i < MI; i++)
#pragma unroll
        for (int j = 0; j < NI; j++) acc[i][j] = (f32x4){0.f, 0.f, 0.f, 0.f};

    const int fragoff = ((q ^ (m & 3)) << 3); // swizzled 8-short block offset

    for (int k0 = 0; k0 < K2; k0 += 32) {
        // ---- stage A-tile(BM x 32) and B-tile(BN x 32) via global_load_lds ----
#pragma unroll
        for (int t = w; t < NT; t += 4) {
            const bool isA = (t < BM / 16);
            const int  tt  = isA ? t : t - BM / 16;
            const int  rl  = tt * 16 + rsub;              // local LDS row
            const int  blk = bsel ^ (rl & 3);             // swizzle on load side
            const short* g = isA ? (A + (size_t)(m0 + rl) * K2 + k0 + blk * 8)
                                 : (B + (size_t)(n0 + rl) * K2 + k0 + blk * 8);
            short* lb = (isA ? As : Bs) + tt * 16 * 32;   // wave-uniform base
            gld_lds16(lb, g);
        }
        __syncthreads();   // drains vmcnt(0): staging complete

        bf16x8 af[MI], bfr[NI];
#pragma unroll
        for (int i = 0; i < MI; i++)
            af[i] = *(const bf16x8*)&As[(wr * WM + i * 16 + m) * 32 + fragoff];
#pragma unroll
        for (int j = 0; j < NI; j++)
            bfr[j] = *(const bf16x8*)&Bs[(wc * WN + j * 16 + m) * 32 + fragoff];
#pragma unroll
        for (int i = 0; i < MI; i++)
#pragma unroll
            for (int j = 0; j < NI; j++)
                acc[i][j] = __builtin_amdgcn_mfma_f32_16x16x32_bf16(
                    af[i], bfr[j], acc[i][j], 0, 0, 0);
        __syncthreads();   // tile consumed; safe to overwrite next iter
    }

    // ---- epilogue: C/D layout col=lane&15, row=q*4+reg ----
#pragma unroll
    for (int i = 0; i < MI; i++) {
#pragma unroll
        for (int j = 0; j < NI; j++) {
            const int col = n0 + wc * WN + j * 16 + m;
            if (col >= N) continue;
            const int rowb = m0 + wr * WM + i * 16 + q * 4;
#pragma unroll
            for (int r = 0; r < 4; r++)
                C[(size_t)(rowb + r) * ldc + col] = acc[i][j][r];
        }
    }
}

// ---------------------------------------------------------------------------
// split conversions
// ---------------------------------------------------------------------------
__global__ __launch_bounds__(256) void split_x(const float* __restrict__ x,
                                               short* __restrict__ Ax) {
    int idx = blockIdx.x * 256 + threadIdx.x;          // 4096*768
    int mrow = idx / DIM, k = idx - mrow * DIM;
    float v = x[idx];
    unsigned short hi = f2bf(v);
    unsigned short lo = f2bf(v - bf2f(hi));
    short* row = Ax + (size_t)mrow * K1;
    row[k] = (short)hi; row[DIM + k] = (short)hi; row[2 * DIM + k] = (short)lo;
}

__global__ __launch_bounds__(256) void split_win(const float* __restrict__ Wi,
                                                 short* __restrict__ Bw) {
    int idx = blockIdx.x * 256 + threadIdx.x;          // 4736*768
    int n = idx / DIM, k = idx - n * DIM;
    float v = (n < NCOLS) ? Wi[(size_t)n * DIM + k] : 0.f;
    unsigned short hi = f2bf(v);
    unsigned short lo = f2bf(v - bf2f(hi));
    short* row = Bw + (size_t)n * K1;
    row[k] = (short)hi; row[DIM + k] = (short)lo; row[2 * DIM + k] = (short)hi;
}

__global__ __launch_bounds__(256) void split_wout(const float* __restrict__ Wo,
                                                  short* __restrict__ Bo) {
    int idx = blockIdx.x * 256 + threadIdx.x;          // 768*1536
    int n = idx / DINNER, k = idx - n * DINNER;
    float v = Wo[idx];
    unsigned short hi = f2bf(v);
    unsigned short lo = f2bf(v - bf2f(hi));
    short* row = Bo + (size_t)n * K2G;
    row[k] = (short)hi; row[DINNER + k] = (short)lo; row[2 * DINNER + k] = (short)hi;
}

// compact B_ssm/C_ssm columns of xz into dense arrays
__global__ __launch_bounds__(256) void bc_compact(const float* __restrict__ xz,
                                                  float* __restrict__ Bc,
                                                  float* __restrict__ Cc) {
    int i = blockIdx.x * 256 + threadIdx.x;            // 4096*32
    int l = i >> 5, j = i & 31;
    float v = xz[(size_t)l * NCOLS + 3072 + j];
    if (j < 16) Bc[l * DSTATE + j] = v;
    else        Cc[l * DSTATE + (j - 16)] = v;
}

// ---------------------------------------------------------------------------
// scan phase 1 (conv+silu+softplus fused, rolling window):
//   per chunk: local scan h=0 -> h_end ; aprod = exp(A * sum(dt))
// ---------------------------------------------------------------------------
__global__ __launch_bounds__(256) void scan1_kernel(const float* __restrict__ xz,
                                                    const float* __restrict__ Wc,
                                                    const float* __restrict__ Bcp,
                                                    const float* __restrict__ A_log,
                                                    float* __restrict__ aprod,
                                                    float* __restrict__ hend) {
    __shared__ float Bs[CLEN * DSTATE];
    const int d  = blockIdx.x * 256 + threadIdx.x;
    const int c  = blockIdx.y;
    const int l0 = c * CLEN;
    for (int i = threadIdx.x; i < CLEN * DSTATE; i += 256)
        Bs[i] = Bcp[l0 * DSTATE + i];
    float Areg[DSTATE];
#pragma unroll
    for (int n = 0; n < DSTATE; n++) Areg[n] = -__expf(A_log[d * DSTATE + n]);
    const float w0 = Wc[d * 3 + 0], w1 = Wc[d * 3 + 1], w2 = Wc[d * 3 + 2];
    float xm = (l0 > 0) ? xz[(size_t)(l0 - 1) * NCOLS + d] : 0.f;
    float x0 = xz[(size_t)l0 * NCOLS + d];
    __syncthreads();

    float h[DSTATE];
#pragma unroll
    for (int n = 0; n < DSTATE; n++) h[n] = 0.f;
    float S = 0.f;

    for (int t = 0; t < CLEN; t++) {
        const int l = l0 + t;
        float xp = (l + 1 < LSEQ) ? xz[(size_t)(l + 1) * NCOLS + d] : 0.f;
        float v  = xm * w0 + x0 * w1 + xp * w2;
        float xcv = __fdividef(v, 1.f + __expf(-v));                 // silu(conv)
        float draw = xz[(size_t)l * NCOLS + 3104 + d];
        float dtv = (draw > 20.f) ? draw : __logf(1.f + __expf(draw)); // softplus
        float u = dtv * xcv;
        S += dtv;
#pragma unroll
        for (int n = 0; n < DSTATE; n++) {
            float e = __expf(dtv * Areg[n]);
            h[n] = e * h[n] + u * Bs[t * DSTATE + n];
        }
        xm = x0; x0 = xp;
    }
#pragma unroll
    for (int n = 0; n < DSTATE; n++) {
        size_t idx = ((size_t)c * DSTATE + n) * DINNER + d;
        aprod[idx] = __expf(S * Areg[n]);
        hend[idx]  = h[n];
    }
}

// ---------------------------------------------------------------------------
// scan phase 2: sequential over the 64 chunk summaries
// ---------------------------------------------------------------------------
__global__ __launch_bounds__(256) void scan2_kernel(const float* __restrict__ aprod,
                                                    const float* __restrict__ hend,
                                                    float* __restrict__ hinit) {
    const int g = blockIdx.x * 256 + threadIdx.x;   // n*1536 + d
    float h = 0.f;
    for (int c = 0; c < NCH; c++) {
        size_t idx = (size_t)c * (DSTATE * DINNER) + g;
        hinit[idx] = h;
        h = aprod[idx] * h + hend[idx];
    }
}

// ---------------------------------------------------------------------------
// scan phase 3: replay from h_init; emit split-bf16 A-operand for GEMM2:
//   yv = (y + xc*D)*silu(z);  Ay[l][d]=hi, [1536+d]=hi, [3072+d]=lo
// ---------------------------------------------------------------------------
__global__ __launch_bounds__(256) void scan3_kernel(const float* __restrict__ xz,
                                                    const float* __restrict__ Wc,
                                                    const float* __restrict__ Bcp,
                                                    const float* __restrict__ Ccp,
                                                    const float* __restrict__ A_log,
                                                    const float* __restrict__ hinit,
                                                    const float* __restrict__ Dp,
                                                    short* __restrict__ Ay) {
    __shared__ float Bs[CLEN * DSTATE];
    __shared__ float Cs[CLEN * DSTATE];
    const int d  = blockIdx.x * 256 + threadIdx.x;
    const int c  = blockIdx.y;
    const int l0 = c * CLEN;
    for (int i = threadIdx.x; i < CLEN * DSTATE; i += 256) {
        Bs[i] = Bcp[l0 * DSTATE + i];
        Cs[i] = Ccp[l0 * DSTATE + i];
    }
    float Areg[DSTATE];
#pragma unroll
    for (int n = 0; n < DSTATE; n++) Areg[n] = -__expf(A_log[d * DSTATE + n]);
    float h[DSTATE];
#pragma unroll
    for (int n = 0; n < DSTATE; n++)
        h[n] = hinit[((size_t)c * DSTATE + n) * DINNER + d];
    const float Dv = Dp[d];
    const float w0 = Wc[d * 3 + 0], w1 = Wc[d * 3 + 1], w2 = Wc[d * 3 + 2];
    float xm = (l0 > 0) ? xz[(size_t)(l0 - 1) * NCOLS + d] : 0.f;
    float x0 = xz[(size_t)l0 * NCOLS + d];
    __syncthreads();

    for (int t = 0; t < CLEN; t++) {
        const int l = l0 + t;
        float xp = (l + 1 < LSEQ) ? xz[(size_t)(l + 1) * NCOLS + d] : 0.f;
        float v  = xm * w0 + x0 * w1 + xp * w2;
        float xcv = __fdividef(v, 1.f + __expf(-v));
        float draw = xz[(size_t)l * NCOLS + 3104 + d];
        float dtv = (draw > 20.f) ? draw : __logf(1.f + __expf(draw));
        float u = dtv * xcv;
        float y = 0.f;
#pragma unroll
        for (int n = 0; n < DSTATE; n++) {
            float e = __expf(dtv * Areg[n]);
            h[n] = e * h[n] + u * Bs[t * DSTATE + n];
            y += h[n] * Cs[t * DSTATE + n];
        }
        float z  = xz[(size_t)l * NCOLS + DINNER + d];
        float sz = __fdividef(z, 1.f + __expf(-z));
        float yv = (y + xcv * Dv) * sz;
        unsigned short hi = f2bf(yv);
        unsigned short lo = f2bf(yv - bf2f(hi));
        short* row = Ay + (size_t)l * K2G;
        row[d] = (short)hi; row[DINNER + d] = (short)hi; row[2 * DINNER + d] = (short)lo;
        xm = x0; x0 = xp;
    }
}

// ---------------------------------------------------------------------------
extern "C" void kernel_launch(void* const* d_in, const int* in_sizes, int n_in,
                              void* d_out, int out_size, void* d_ws, size_t ws_size,
                              hipStream_t stream) {
    const float* x     = (const float*)d_in[0];   // [4096, 768]
    const float* W_in  = (const float*)d_in[1];   // [4640, 768]
    const float* W_conv= (const float*)d_in[2];   // [1536, 3]
    const float* W_out = (const float*)d_in[3];   // [768, 1536]
    const float* A_log = (const float*)d_in[4];   // [1536, 16]
    const float* Dp    = (const float*)d_in[5];   // [1536]
    float* out = (float*)d_out;                   // [4096, 768]

    // workspace carve-up (~155 MB)
    float* ws  = (float*)d_ws;
    float* xz  = ws;                                  // 19,005,440 f
    float* Bc  = xz + (size_t)LSEQ * NCOLS;           // 65,536
    float* Cc  = Bc + (size_t)LSEQ * DSTATE;          // 65,536
    float* ap  = Cc + (size_t)LSEQ * DSTATE;          // 1,572,864
    float* he  = ap + (size_t)NCH * DSTATE * DINNER;  // 1,572,864
    float* hi  = he + (size_t)NCH * DSTATE * DINNER;  // 1,572,864
    short* AxAy= (short*)(hi + (size_t)NCH * DSTATE * DINNER); // max(4096*2304, 4096*4608) shorts
    short* Bw  = AxAy + (size_t)LSEQ * K2G;           // max(4736*2304, 768*4608) shorts
    short* Ax  = AxAy;                                // GEMM1 A (dead after gemm1)
    short* Ay  = AxAy;                                // GEMM2 A (written by scan3)
    short* Bo  = Bw;                                  // GEMM2 B (reuses Bw region)

    // 0) split conversions
    split_x   <<<(LSEQ * DIM) / 256, 256, 0, stream>>>(x, Ax);
    split_win <<<(NPAD * DIM) / 256, 256, 0, stream>>>(W_in, Bw);
    // 1) xz = x @ W_in^T  (split-bf16 MFMA, K'=2304)
    gemm_bf16_nt<128, 128, 64, 64><<<dim3(NPAD / 128, LSEQ / 128), 256, 0, stream>>>(
        Ax, Bw, xz, LSEQ, NCOLS, K1, NCOLS);
    // 2) compact B/C
    bc_compact<<<(LSEQ * 32) / 256, 256, 0, stream>>>(xz, Bc, Cc);
    // 3) chunked scan (conv/silu/softplus fused into scan1/scan3)
    scan1_kernel<<<dim3(DINNER / 256, NCH), 256, 0, stream>>>(
        xz, W_conv, Bc, A_log, ap, he);
    scan2_kernel<<<(DINNER * DSTATE) / 256, 256, 0, stream>>>(ap, he, hi);
    scan3_kernel<<<dim3(DINNER / 256, NCH), 256, 0, stream>>>(
        xz, W_conv, Bc, Cc, A_log, hi, Dp, Ay);
    // 3b) W_out split (Bw region is dead now)
    split_wout<<<(DIM * DINNER) / 256, 256, 0, stream>>>(W_out, Bo);
    // 4) out = yf @ W_out^T  (split-bf16 MFMA, K'=4608)
    gemm_bf16_nt<64, 128, 32, 64><<<dim3(DIM / 128, LSEQ / 64), 256, 0, stream>>>(
        Ay, Bo, out, LSEQ, DIM, K2G, DIM);
}

// Round 3
// 318.854 us; speedup vs baseline: 2.6030x; 1.3352x over previous
//
#include <hip/hip_runtime.h>
#include <hip/hip_bf16.h>
#include <math.h>

// Problem constants
#define LSEQ   4096
#define DIM    768
#define DINNER 1536
#define DSTATE 16
#define NCOLS  4640          // 3*DINNER + 2*DSTATE
#define NCH    64            // scan chunks
#define CLEN   64            // steps per chunk
#define NPAD   4736          // W_in rows padded to 37*128

typedef _Float16 f16;
typedef __attribute__((ext_vector_type(8))) _Float16 f16x8;
typedef __attribute__((ext_vector_type(4))) float f32x4;

// W pre-scale (exact power of two): keeps W_lo in fp16 normal range.
#define WSCALE   64.0f
#define WDESCALE 0.015625f

// async global(16B/lane) -> LDS staging
__device__ __forceinline__ void gld_lds16(void* lds_dst, const void* gsrc) {
    __builtin_amdgcn_global_load_lds(
        (__attribute__((address_space(1))) void*)(gsrc),
        (__attribute__((address_space(3))) void*)(lds_dst), 16, 0, 0);
}

// ---------------------------------------------------------------------------
// fp16 split GEMM:  C[M,N](fp32) = cscale * A[M,K](f16) * (Bh+Bl)[N,K]^T
// B stored as [hi(0..K) | lo(0..K)] rows, ldb = 2K. Both planes feed the SAME
// accumulator (W pre-scaled by 64, descale in epilogue).
// 256 threads = 4 waves, wave tile WM x WN, (BM/WM)*(BN/WN) == 4.
// XCD swizzle: flat grid 8*P, idx=(b&7)*P+(b>>3), row-major in XCD slab.
// ---------------------------------------------------------------------------
template<int BM, int BN, int WM, int WN, int NCB>
__global__ __launch_bounds__(256) void gemm_f16_split(const f16* __restrict__ A,
                                                      const f16* __restrict__ B,
                                                      float* __restrict__ C,
                                                      int M, int N, int K, int ldc,
                                                      float cscale) {
    constexpr int MI  = WM / 16;
    constexpr int NI  = WN / 16;
    constexpr int NWN = BN / WN;
    constexpr int nA  = BM / 16;
    constexpr int nB  = BN / 16;
    constexpr int NT  = nA + 2 * nB;

    __shared__ __align__(16) f16 As[BM * 32];
    __shared__ __align__(16) f16 Bs[2 * BN * 32];   // [hi | lo]

    // XCD-aware block swizzle (row-major within each XCD's slab)
    const int P   = gridDim.x >> 3;
    const int idx = (blockIdx.x & 7) * P + (blockIdx.x >> 3);
    const int m0  = (idx / NCB) * BM;
    const int n0  = (idx % NCB) * BN;

    const int tid  = threadIdx.x;
    const int w    = tid >> 6;
    const int lane = tid & 63;
    const int wr   = w / NWN;
    const int wc   = w % NWN;
    const int m    = lane & 15;
    const int q    = lane >> 4;
    const int rsub = lane >> 2;               // staging row within 16-row group
    const int bsel = lane & 3;                // staging 16B-block index
    const int ldb  = 2 * K;

    f32x4 acc[MI][NI];
#pragma unroll
    for (int i = 0; i < MI; i++)
#pragma unroll
        for (int j = 0; j < NI; j++) acc[i][j] = (f32x4){0.f, 0.f, 0.f, 0.f};

    const int fragoff = ((q ^ (m & 3)) << 3);

    for (int k0 = 0; k0 < K; k0 += 32) {
#pragma unroll
        for (int t = w; t < NT; t += 4) {
            const f16* g; f16* lb; int rl;
            if (t < nA) {
                rl = t * 16 + rsub;
                g  = A + (size_t)(m0 + rl) * K + k0 + (bsel ^ (rl & 3)) * 8;
                lb = As + t * 16 * 32;
            } else if (t < nA + nB) {
                int tt = t - nA; rl = tt * 16 + rsub;
                g  = B + (size_t)(n0 + rl) * ldb + k0 + (bsel ^ (rl & 3)) * 8;
                lb = Bs + tt * 16 * 32;
            } else {
                int tt = t - nA - nB; rl = tt * 16 + rsub;
                g  = B + (size_t)(n0 + rl) * ldb + K + k0 + (bsel ^ (rl & 3)) * 8;
                lb = Bs + (nB + tt) * 16 * 32;
            }
            gld_lds16(lb, g);
        }
        __syncthreads();   // drains vmcnt(0): staging complete

        f16x8 af[MI], bh[NI], bl[NI];
#pragma unroll
        for (int i = 0; i < MI; i++)
            af[i] = *(const f16x8*)&As[(wr * WM + i * 16 + m) * 32 + fragoff];
#pragma unroll
        for (int j = 0; j < NI; j++) {
            bh[j] = *(const f16x8*)&Bs[(wc * WN + j * 16 + m) * 32 + fragoff];
            bl[j] = *(const f16x8*)&Bs[BN * 32 + (wc * WN + j * 16 + m) * 32 + fragoff];
        }
#pragma unroll
        for (int i = 0; i < MI; i++)
#pragma unroll
            for (int j = 0; j < NI; j++) {
                acc[i][j] = __builtin_amdgcn_mfma_f32_16x16x32_f16(af[i], bh[j], acc[i][j], 0, 0, 0);
                acc[i][j] = __builtin_amdgcn_mfma_f32_16x16x32_f16(af[i], bl[j], acc[i][j], 0, 0, 0);
            }
        __syncthreads();
    }

    // epilogue: C/D layout col=lane&15, row=q*4+reg ; descale
#pragma unroll
    for (int i = 0; i < MI; i++) {
#pragma unroll
        for (int j = 0; j < NI; j++) {
            const int col = n0 + wc * WN + j * 16 + m;
            if (col >= N) continue;
            const int rowb = m0 + wr * WM + i * 16 + q * 4;
#pragma unroll
            for (int r = 0; r < 4; r++)
                C[(size_t)(rowb + r) * ldc + col] = acc[i][j][r] * cscale;
        }
    }
}

// ---------------------------------------------------------------------------
// conversions
// ---------------------------------------------------------------------------
__global__ __launch_bounds__(256) void cvt_x(const float* __restrict__ x,
                                             f16* __restrict__ Ax) {
    int i = (blockIdx.x * 256 + threadIdx.x) * 4;       // 4096*768
    float4 v = *(const float4*)(x + i);
    Ax[i] = (f16)v.x; Ax[i+1] = (f16)v.y; Ax[i+2] = (f16)v.z; Ax[i+3] = (f16)v.w;
}

__global__ __launch_bounds__(256) void cvt_win(const float* __restrict__ Wi,
                                               f16* __restrict__ Bw) {
    int i = (blockIdx.x * 256 + threadIdx.x) * 4;       // 4736*768
    int n = i / DIM, k = i - n * DIM;
    f16* row = Bw + (size_t)n * (2 * DIM) + k;
    if (n < NCOLS) {
        float4 v = *(const float4*)(Wi + (size_t)n * DIM + k);
        float a[4] = {v.x * WSCALE, v.y * WSCALE, v.z * WSCALE, v.w * WSCALE};
#pragma unroll
        for (int j = 0; j < 4; j++) {
            f16 hi = (f16)a[j];
            row[j] = hi; row[DIM + j] = (f16)(a[j] - (float)hi);
        }
    } else {
#pragma unroll
        for (int j = 0; j < 4; j++) { row[j] = (f16)0.f; row[DIM + j] = (f16)0.f; }
    }
}

__global__ __launch_bounds__(256) void cvt_wout(const float* __restrict__ Wo,
                                                f16* __restrict__ Bo) {
    int i = (blockIdx.x * 256 + threadIdx.x) * 4;       // 768*1536
    int n = i / DINNER, k = i - n * DINNER;
    float4 v = *(const float4*)(Wo + i);
    float a[4] = {v.x * WSCALE, v.y * WSCALE, v.z * WSCALE, v.w * WSCALE};
    f16* row = Bo + (size_t)n * (2 * DINNER) + k;
#pragma unroll
    for (int j = 0; j < 4; j++) {
        f16 hi = (f16)a[j];
        row[j] = hi; row[DINNER + j] = (f16)(a[j] - (float)hi);
    }
}

// compact B_ssm/C_ssm columns of xz
__global__ __launch_bounds__(256) void bc_compact(const float* __restrict__ xz,
                                                  float* __restrict__ Bc,
                                                  float* __restrict__ Cc) {
    int i = blockIdx.x * 256 + threadIdx.x;            // 4096*32
    int l = i >> 5, j = i & 31;
    float v = xz[(size_t)l * NCOLS + 3072 + j];
    if (j < 16) Bc[l * DSTATE + j] = v;
    else        Cc[l * DSTATE + (j - 16)] = v;
}

// ---------------------------------------------------------------------------
// scan phase 1: conv+silu+softplus fused; local scan h=0 -> h_end; aprod
// ---------------------------------------------------------------------------
__global__ __launch_bounds__(256) void scan1_kernel(const float* __restrict__ xz,
                                                    const float* __restrict__ Wc,
                                                    const float* __restrict__ Bcp,
                                                    const float* __restrict__ A_log,
                                                    float* __restrict__ aprod,
                                                    float* __restrict__ hend) {
    __shared__ float Bs[CLEN * DSTATE];
    const int d  = blockIdx.x * 256 + threadIdx.x;
    const int c  = blockIdx.y;
    const int l0 = c * CLEN;
    for (int i = threadIdx.x; i < CLEN * DSTATE; i += 256)
        Bs[i] = Bcp[l0 * DSTATE + i];
    float Areg[DSTATE];
#pragma unroll
    for (int n = 0; n < DSTATE; n++) Areg[n] = -__expf(A_log[d * DSTATE + n]);
    const float w0 = Wc[d * 3 + 0], w1 = Wc[d * 3 + 1], w2 = Wc[d * 3 + 2];
    float xm = (l0 > 0) ? xz[(size_t)(l0 - 1) * NCOLS + d] : 0.f;
    float x0 = xz[(size_t)l0 * NCOLS + d];
    __syncthreads();

    float h[DSTATE];
#pragma unroll
    for (int n = 0; n < DSTATE; n++) h[n] = 0.f;
    float S = 0.f;

    for (int t = 0; t < CLEN; t++) {
        const int l = l0 + t;
        float xp = (l + 1 < LSEQ) ? xz[(size_t)(l + 1) * NCOLS + d] : 0.f;
        float v  = xm * w0 + x0 * w1 + xp * w2;
        float xcv = __fdividef(v, 1.f + __expf(-v));
        float draw = xz[(size_t)l * NCOLS + 3104 + d];
        float dtv = (draw > 20.f) ? draw : __logf(1.f + __expf(draw));
        float u = dtv * xcv;
        S += dtv;
#pragma unroll
        for (int n = 0; n < DSTATE; n++) {
            float e = __expf(dtv * Areg[n]);
            h[n] = e * h[n] + u * Bs[t * DSTATE + n];
        }
        xm = x0; x0 = xp;
    }
#pragma unroll
    for (int n = 0; n < DSTATE; n++) {
        size_t idx = ((size_t)c * DSTATE + n) * DINNER + d;
        aprod[idx] = __expf(S * Areg[n]);
        hend[idx]  = h[n];
    }
}

// ---------------------------------------------------------------------------
// scan phase 2: sequential over 64 chunk summaries
// ---------------------------------------------------------------------------
__global__ __launch_bounds__(256) void scan2_kernel(const float* __restrict__ aprod,
                                                    const float* __restrict__ hend,
                                                    float* __restrict__ hinit) {
    const int g = blockIdx.x * 256 + threadIdx.x;
    float h = 0.f;
    for (int c = 0; c < NCH; c++) {
        size_t idx = (size_t)c * (DSTATE * DINNER) + g;
        hinit[idx] = h;
        h = aprod[idx] * h + hend[idx];
    }
}

// ---------------------------------------------------------------------------
// scan phase 3: replay from h_init; emit yf as plain fp16 (GEMM2 A-operand)
// ---------------------------------------------------------------------------
__global__ __launch_bounds__(256) void scan3_kernel(const float* __restrict__ xz,
                                                    const float* __restrict__ Wc,
                                                    const float* __restrict__ Bcp,
                                                    const float* __restrict__ Ccp,
                                                    const float* __restrict__ A_log,
                                                    const float* __restrict__ hinit,
                                                    const float* __restrict__ Dp,
                                                    f16* __restrict__ Ay) {
    __shared__ float Bs[CLEN * DSTATE];
    __shared__ float Cs[CLEN * DSTATE];
    const int d  = blockIdx.x * 256 + threadIdx.x;
    const int c  = blockIdx.y;
    const int l0 = c * CLEN;
    for (int i = threadIdx.x; i < CLEN * DSTATE; i += 256) {
        Bs[i] = Bcp[l0 * DSTATE + i];
        Cs[i] = Ccp[l0 * DSTATE + i];
    }
    float Areg[DSTATE];
#pragma unroll
    for (int n = 0; n < DSTATE; n++) Areg[n] = -__expf(A_log[d * DSTATE + n]);
    float h[DSTATE];
#pragma unroll
    for (int n = 0; n < DSTATE; n++)
        h[n] = hinit[((size_t)c * DSTATE + n) * DINNER + d];
    const float Dv = Dp[d];
    const float w0 = Wc[d * 3 + 0], w1 = Wc[d * 3 + 1], w2 = Wc[d * 3 + 2];
    float xm = (l0 > 0) ? xz[(size_t)(l0 - 1) * NCOLS + d] : 0.f;
    float x0 = xz[(size_t)l0 * NCOLS + d];
    __syncthreads();

    for (int t = 0; t < CLEN; t++) {
        const int l = l0 + t;
        float xp = (l + 1 < LSEQ) ? xz[(size_t)(l + 1) * NCOLS + d] : 0.f;
        float v  = xm * w0 + x0 * w1 + xp * w2;
        float xcv = __fdividef(v, 1.f + __expf(-v));
        float draw = xz[(size_t)l * NCOLS + 3104 + d];
        float dtv = (draw > 20.f) ? draw : __logf(1.f + __expf(draw));
        float u = dtv * xcv;
        float y = 0.f;
#pragma unroll
        for (int n = 0; n < DSTATE; n++) {
            float e = __expf(dtv * Areg[n]);
            h[n] = e * h[n] + u * Bs[t * DSTATE + n];
            y += h[n] * Cs[t * DSTATE + n];
        }
        float z  = xz[(size_t)l * NCOLS + DINNER + d];
        float sz = __fdividef(z, 1.f + __expf(-z));
        Ay[(size_t)l * DINNER + d] = (f16)((y + xcv * Dv) * sz);
        xm = x0; x0 = xp;
    }
}

// ---------------------------------------------------------------------------
extern "C" void kernel_launch(void* const* d_in, const int* in_sizes, int n_in,
                              void* d_out, int out_size, void* d_ws, size_t ws_size,
                              hipStream_t stream) {
    const float* x     = (const float*)d_in[0];
    const float* W_in  = (const float*)d_in[1];
    const float* W_conv= (const float*)d_in[2];
    const float* W_out = (const float*)d_in[3];
    const float* A_log = (const float*)d_in[4];
    const float* Dp    = (const float*)d_in[5];
    float* out = (float*)d_out;

    // workspace carve-up (~134 MB)
    float* ws  = (float*)d_ws;
    float* xz  = ws;                                  // 19,005,440 f
    float* Bc  = xz + (size_t)LSEQ * NCOLS;           // 65,536
    float* Cc  = Bc + (size_t)LSEQ * DSTATE;          // 65,536
    float* ap  = Cc + (size_t)LSEQ * DSTATE;          // 1,572,864
    float* he  = ap + (size_t)NCH * DSTATE * DINNER;  // 1,572,864
    float* hi  = he + (size_t)NCH * DSTATE * DINNER;  // 1,572,864
    f16* Ax = (f16*)(hi + (size_t)NCH * DSTATE * DINNER); // 4096*768
    f16* Ay = Ax + (size_t)LSEQ * DIM;                // 4096*1536
    f16* Bw = Ay + (size_t)LSEQ * DINNER;             // 4736*1536
    f16* Bo = Bw + (size_t)NPAD * 2 * DIM;            // 768*3072

    cvt_x   <<<(LSEQ * DIM) / 1024, 256, 0, stream>>>(x, Ax);
    cvt_win <<<(NPAD * DIM) / 1024, 256, 0, stream>>>(W_in, Bw);
    cvt_wout<<<(DIM * DINNER) / 1024, 256, 0, stream>>>(W_out, Bo);

    // 1) xz = x @ W_in^T : 37x32=1184 blocks, XCD-swizzled 1D grid
    gemm_f16_split<128, 128, 64, 64, 37><<<1184, 256, 0, stream>>>(
        Ax, Bw, xz, LSEQ, NCOLS, DIM, NCOLS, WDESCALE);

    bc_compact<<<(LSEQ * 32) / 256, 256, 0, stream>>>(xz, Bc, Cc);
    scan1_kernel<<<dim3(DINNER / 256, NCH), 256, 0, stream>>>(
        xz, W_conv, Bc, A_log, ap, he);
    scan2_kernel<<<(DINNER * DSTATE) / 256, 256, 0, stream>>>(ap, he, hi);
    scan3_kernel<<<dim3(DINNER / 256, NCH), 256, 0, stream>>>(
        xz, W_conv, Bc, Cc, A_log, hi, Dp, Ay);

    // 4) out = yf @ W_out^T : 12x32=384 blocks
    gemm_f16_split<128, 64, 64, 32, 12><<<384, 256, 0, stream>>>(
        Ay, Bo, out, LSEQ, DIM, DINNER, DIM, WDESCALE);
}

// Round 4
// 290.037 us; speedup vs baseline: 2.8616x; 1.0994x over previous
//
#include <hip/hip_runtime.h>
#include <hip/hip_bf16.h>
#include <math.h>

// Problem constants
#define LSEQ   4096
#define DIM    768
#define DINNER 1536
#define DSTATE 16
#define NCOLS  4640          // 3*DINNER + 2*DSTATE
#define NCH    128           // scan chunks
#define CLEN   32            // steps per chunk
#define NPAD   4736          // W_in rows padded to 37*128

typedef _Float16 f16;
typedef __attribute__((ext_vector_type(8))) _Float16 f16x8;
typedef __attribute__((ext_vector_type(4))) float f32x4;

// W pre-scale (exact power of two): keeps W_lo in fp16 normal range.
#define WSCALE   64.0f
#define WDESCALE 0.015625f

// async global(16B/lane) -> LDS staging
__device__ __forceinline__ void gld_lds16(void* lds_dst, const void* gsrc) {
    __builtin_amdgcn_global_load_lds(
        (__attribute__((address_space(1))) void*)(gsrc),
        (__attribute__((address_space(3))) void*)(lds_dst), 16, 0, 0);
}

// ---------------------------------------------------------------------------
// fp16 split GEMM:  C[M,N](fp32) = cscale * A[M,K](f16) * (Bh+Bl)[N,K]^T
// B stored as [hi(0..K) | lo(0..K)] rows, ldb = 2K; both planes feed the same
// accumulator (W pre-scaled by 64, descaled in epilogue).
// 256 threads = 4 waves; wave tile WM x WN; (BM/WM)*(BN/WN) == 4.
// XCD swizzle: flat grid (8 | grid), idx=(b&7)*P+(b>>3).
//   COLM=true : m0=(idx%NTB)*BM, n0=(idx/NTB)*BN  (NTB = M-tiles; B-locality)
//   COLM=false: m0=(idx/NTB)*BM, n0=(idx%NTB)*BN  (NTB = N-tiles; A-locality)
// ---------------------------------------------------------------------------
template<int BM, int BN, int WM, int WN, int NTB, bool COLM>
__global__ __launch_bounds__(256) void gemm_f16_split(const f16* __restrict__ A,
                                                      const f16* __restrict__ B,
                                                      float* __restrict__ C,
                                                      int M, int N, int K, int ldc,
                                                      float cscale) {
    constexpr int MI  = WM / 16;
    constexpr int NI  = WN / 16;
    constexpr int NWN = BN / WN;
    constexpr int nA  = BM / 16;
    constexpr int nB  = BN / 16;
    constexpr int NT  = nA + 2 * nB;

    __shared__ __align__(16) f16 As[BM * 32];
    __shared__ __align__(16) f16 Bs[2 * BN * 32];   // [hi | lo]

    const int P   = gridDim.x >> 3;
    const int idx = (blockIdx.x & 7) * P + (blockIdx.x >> 3);
    const int m0  = (COLM ? (idx % NTB) : (idx / NTB)) * BM;
    const int n0  = (COLM ? (idx / NTB) : (idx % NTB)) * BN;

    const int tid  = threadIdx.x;
    const int w    = tid >> 6;
    const int lane = tid & 63;
    const int wr   = w / NWN;
    const int wc   = w % NWN;
    const int m    = lane & 15;
    const int q    = lane >> 4;
    const int rsub = lane >> 2;               // staging row within 16-row group
    const int bsel = lane & 3;                // staging 16B-block index
    const int ldb  = 2 * K;

    f32x4 acc[MI][NI];
#pragma unroll
    for (int i = 0; i < MI; i++)
#pragma unroll
        for (int j = 0; j < NI; j++) acc[i][j] = (f32x4){0.f, 0.f, 0.f, 0.f};

    const int fragoff = ((q ^ (m & 3)) << 3);

    for (int k0 = 0; k0 < K; k0 += 32) {
#pragma unroll
        for (int t = w; t < NT; t += 4) {
            const f16* g; f16* lb; int rl;
            if (t < nA) {
                rl = t * 16 + rsub;
                g  = A + (size_t)(m0 + rl) * K + k0 + (bsel ^ (rl & 3)) * 8;
                lb = As + t * 16 * 32;
            } else if (t < nA + nB) {
                int tt = t - nA; rl = tt * 16 + rsub;
                g  = B + (size_t)(n0 + rl) * ldb + k0 + (bsel ^ (rl & 3)) * 8;
                lb = Bs + tt * 16 * 32;
            } else {
                int tt = t - nA - nB; rl = tt * 16 + rsub;
                g  = B + (size_t)(n0 + rl) * ldb + K + k0 + (bsel ^ (rl & 3)) * 8;
                lb = Bs + (nB + tt) * 16 * 32;
            }
            gld_lds16(lb, g);
        }
        __syncthreads();   // drains vmcnt(0): staging complete

        f16x8 af[MI], bh[NI], bl[NI];
#pragma unroll
        for (int i = 0; i < MI; i++)
            af[i] = *(const f16x8*)&As[(wr * WM + i * 16 + m) * 32 + fragoff];
#pragma unroll
        for (int j = 0; j < NI; j++) {
            bh[j] = *(const f16x8*)&Bs[(wc * WN + j * 16 + m) * 32 + fragoff];
            bl[j] = *(const f16x8*)&Bs[BN * 32 + (wc * WN + j * 16 + m) * 32 + fragoff];
        }
#pragma unroll
        for (int i = 0; i < MI; i++)
#pragma unroll
            for (int j = 0; j < NI; j++) {
                acc[i][j] = __builtin_amdgcn_mfma_f32_16x16x32_f16(af[i], bh[j], acc[i][j], 0, 0, 0);
                acc[i][j] = __builtin_amdgcn_mfma_f32_16x16x32_f16(af[i], bl[j], acc[i][j], 0, 0, 0);
            }
        __syncthreads();
    }

    // epilogue: C/D layout col=lane&15, row=q*4+reg ; descale
#pragma unroll
    for (int i = 0; i < MI; i++) {
#pragma unroll
        for (int j = 0; j < NI; j++) {
            const int col = n0 + wc * WN + j * 16 + m;
            if (col >= N) continue;
            const int rowb = m0 + wr * WM + i * 16 + q * 4;
#pragma unroll
            for (int r = 0; r < 4; r++)
                C[(size_t)(rowb + r) * ldc + col] = acc[i][j][r] * cscale;
        }
    }
}

// ---------------------------------------------------------------------------
// merged conversions: Ax (plain f16), Bw (W_in split), Bo (W_out split)
// flat idx over 4-element groups.
// ---------------------------------------------------------------------------
#define E0 (LSEQ * DIM)            // 3,145,728
#define E1 (E0 + NPAD * DIM)       // + 3,637,248
#define E2 (E1 + DIM * DINNER)     // + 1,179,648

__global__ __launch_bounds__(256) void cvt_all(const float* __restrict__ x,
                                               const float* __restrict__ Wi,
                                               const float* __restrict__ Wo,
                                               f16* __restrict__ Ax,
                                               f16* __restrict__ Bw,
                                               f16* __restrict__ Bo) {
    int i = (blockIdx.x * 256 + threadIdx.x) * 4;
    if (i < E0) {
        float4 v = *(const float4*)(x + i);
        Ax[i] = (f16)v.x; Ax[i+1] = (f16)v.y; Ax[i+2] = (f16)v.z; Ax[i+3] = (f16)v.w;
    } else if (i < E1) {
        int e = i - E0;
        int n = e / DIM, k = e - n * DIM;
        f16* row = Bw + (size_t)n * (2 * DIM) + k;
        if (n < NCOLS) {
            float4 v = *(const float4*)(Wi + (size_t)n * DIM + k);
            float a[4] = {v.x * WSCALE, v.y * WSCALE, v.z * WSCALE, v.w * WSCALE};
#pragma unroll
            for (int j = 0; j < 4; j++) {
                f16 hi = (f16)a[j];
                row[j] = hi; row[DIM + j] = (f16)(a[j] - (float)hi);
            }
        } else {
#pragma unroll
            for (int j = 0; j < 4; j++) { row[j] = (f16)0.f; row[DIM + j] = (f16)0.f; }
        }
    } else if (i < E2) {
        int e = i - E1;
        int n = e / DINNER, k = e - n * DINNER;
        float4 v = *(const float4*)(Wo + e);
        float a[4] = {v.x * WSCALE, v.y * WSCALE, v.z * WSCALE, v.w * WSCALE};
        f16* row = Bo + (size_t)n * (2 * DINNER) + k;
#pragma unroll
        for (int j = 0; j < 4; j++) {
            f16 hi = (f16)a[j];
            row[j] = hi; row[DINNER + j] = (f16)(a[j] - (float)hi);
        }
    }
}

// ---------------------------------------------------------------------------
// scan phase 1: conv+silu+softplus fused; local scan h=0 -> h_end; aprod.
// B staged into LDS directly from xz. Rolling prefetch of next-step loads.
// grid (6, NCH) x 256
// ---------------------------------------------------------------------------
__global__ __launch_bounds__(256) void scan1_kernel(const float* __restrict__ xz,
                                                    const float* __restrict__ Wc,
                                                    const float* __restrict__ A_log,
                                                    float* __restrict__ aprod,
                                                    float* __restrict__ hend) {
    __shared__ float Bs[CLEN * DSTATE];
    const int d  = blockIdx.x * 256 + threadIdx.x;
    const int c  = blockIdx.y;
    const int l0 = c * CLEN;
    for (int i = threadIdx.x; i < CLEN * DSTATE; i += 256)
        Bs[i] = xz[(size_t)(l0 + (i >> 4)) * NCOLS + 3072 + (i & 15)];
    float Areg[DSTATE];
#pragma unroll
    for (int n = 0; n < DSTATE; n++) Areg[n] = -__expf(A_log[d * DSTATE + n]);
    const float w0 = Wc[d * 3 + 0], w1 = Wc[d * 3 + 1], w2 = Wc[d * 3 + 2];
    float xm = (l0 > 0) ? xz[(size_t)(l0 - 1) * NCOLS + d] : 0.f;
    float x0 = xz[(size_t)l0 * NCOLS + d];
    float ld_xp   = xz[(size_t)(l0 + 1) * NCOLS + d];
    float ld_draw = xz[(size_t)l0 * NCOLS + 3104 + d];
    __syncthreads();

    float h[DSTATE];
#pragma unroll
    for (int n = 0; n < DSTATE; n++) h[n] = 0.f;
    float S = 0.f;

    for (int t = 0; t < CLEN; t++) {
        const int l = l0 + t;
        float xp = ld_xp, draw = ld_draw;
        if (t + 1 < CLEN) {
            ld_xp   = (l + 2 < LSEQ) ? xz[(size_t)(l + 2) * NCOLS + d] : 0.f;
            ld_draw = xz[(size_t)(l + 1) * NCOLS + 3104 + d];
        }
        float v  = xm * w0 + x0 * w1 + xp * w2;
        float xcv = __fdividef(v, 1.f + __expf(-v));
        float dtv = (draw > 20.f) ? draw : __logf(1.f + __expf(draw));
        float u = dtv * xcv;
        S += dtv;
#pragma unroll
        for (int n = 0; n < DSTATE; n++) {
            float e = __expf(dtv * Areg[n]);
            h[n] = e * h[n] + u * Bs[t * DSTATE + n];
        }
        xm = x0; x0 = xp;
    }
#pragma unroll
    for (int n = 0; n < DSTATE; n++) {
        size_t idx = ((size_t)c * DSTATE + n) * DINNER + d;
        aprod[idx] = __expf(S * Areg[n]);
        hend[idx]  = h[n];
    }
}

// ---------------------------------------------------------------------------
// scan phase 2: sequential over NCH chunk summaries, pipelined loads
// ---------------------------------------------------------------------------
__global__ __launch_bounds__(256) void scan2_kernel(const float* __restrict__ aprod,
                                                    const float* __restrict__ hend,
                                                    float* __restrict__ hinit) {
    const int g = blockIdx.x * 256 + threadIdx.x;
    const size_t S = (size_t)DSTATE * DINNER;
    size_t idx = g;
    float a = aprod[idx], e = hend[idx];
    float h = 0.f;
#pragma unroll 4
    for (int c = 0; c < NCH; c++) {
        float ac = a, ec = e;
        if (c + 1 < NCH) { a = aprod[idx + S]; e = hend[idx + S]; }
        hinit[idx] = h;
        h = ac * h + ec;
        idx += S;
    }
}

// ---------------------------------------------------------------------------
// scan phase 3: replay from h_init; emit yf as plain f16 (GEMM2 A-operand)
// ---------------------------------------------------------------------------
__global__ __launch_bounds__(256) void scan3_kernel(const float* __restrict__ xz,
                                                    const float* __restrict__ Wc,
                                                    const float* __restrict__ A_log,
                                                    const float* __restrict__ hinit,
                                                    const float* __restrict__ Dp,
                                                    f16* __restrict__ Ay) {
    __shared__ float Bs[CLEN * DSTATE];
    __shared__ float Cs[CLEN * DSTATE];
    const int d  = blockIdx.x * 256 + threadIdx.x;
    const int c  = blockIdx.y;
    const int l0 = c * CLEN;
    for (int i = threadIdx.x; i < CLEN * DSTATE; i += 256) {
        size_t roff = (size_t)(l0 + (i >> 4)) * NCOLS;
        Bs[i] = xz[roff + 3072 + (i & 15)];
        Cs[i] = xz[roff + 3088 + (i & 15)];
    }
    float Areg[DSTATE];
#pragma unroll
    for (int n = 0; n < DSTATE; n++) Areg[n] = -__expf(A_log[d * DSTATE + n]);
    float h[DSTATE];
#pragma unroll
    for (int n = 0; n < DSTATE; n++)
        h[n] = hinit[((size_t)c * DSTATE + n) * DINNER + d];
    const float Dv = Dp[d];
    const float w0 = Wc[d * 3 + 0], w1 = Wc[d * 3 + 1], w2 = Wc[d * 3 + 2];
    float xm = (l0 > 0) ? xz[(size_t)(l0 - 1) * NCOLS + d] : 0.f;
    float x0 = xz[(size_t)l0 * NCOLS + d];
    float ld_xp   = xz[(size_t)(l0 + 1) * NCOLS + d];
    float ld_draw = xz[(size_t)l0 * NCOLS + 3104 + d];
    float ld_z    = xz[(size_t)l0 * NCOLS + DINNER + d];
    __syncthreads();

    for (int t = 0; t < CLEN; t++) {
        const int l = l0 + t;
        float xp = ld_xp, draw = ld_draw, zv = ld_z;
        if (t + 1 < CLEN) {
            ld_xp   = (l + 2 < LSEQ) ? xz[(size_t)(l + 2) * NCOLS + d] : 0.f;
            ld_draw = xz[(size_t)(l + 1) * NCOLS + 3104 + d];
            ld_z    = xz[(size_t)(l + 1) * NCOLS + DINNER + d];
        }
        float v  = xm * w0 + x0 * w1 + xp * w2;
        float xcv = __fdividef(v, 1.f + __expf(-v));
        float dtv = (draw > 20.f) ? draw : __logf(1.f + __expf(draw));
        float u = dtv * xcv;
        float y = 0.f;
#pragma unroll
        for (int n = 0; n < DSTATE; n++) {
            float e = __expf(dtv * Areg[n]);
            h[n] = e * h[n] + u * Bs[t * DSTATE + n];
            y += h[n] * Cs[t * DSTATE + n];
        }
        float sz = __fdividef(zv, 1.f + __expf(-zv));
        Ay[(size_t)l * DINNER + d] = (f16)((y + xcv * Dv) * sz);
        xm = x0; x0 = xp;
    }
}

// ---------------------------------------------------------------------------
extern "C" void kernel_launch(void* const* d_in, const int* in_sizes, int n_in,
                              void* d_out, int out_size, void* d_ws, size_t ws_size,
                              hipStream_t stream) {
    const float* x     = (const float*)d_in[0];
    const float* W_in  = (const float*)d_in[1];
    const float* W_conv= (const float*)d_in[2];
    const float* W_out = (const float*)d_in[3];
    const float* A_log = (const float*)d_in[4];
    const float* Dp    = (const float*)d_in[5];
    float* out = (float*)d_out;

    // workspace carve-up (~152 MB)
    float* ws  = (float*)d_ws;
    float* xz  = ws;                                  // 19,005,440 f
    float* ap  = xz + (size_t)LSEQ * NCOLS;           // 3,145,728
    float* he  = ap + (size_t)NCH * DSTATE * DINNER;  // 3,145,728
    float* hi  = he + (size_t)NCH * DSTATE * DINNER;  // 3,145,728
    f16* Ax = (f16*)(hi + (size_t)NCH * DSTATE * DINNER); // 4096*768
    f16* Ay = Ax + (size_t)LSEQ * DIM;                // 4096*1536
    f16* Bw = Ay + (size_t)LSEQ * DINNER;             // 4736*1536
    f16* Bo = Bw + (size_t)NPAD * 2 * DIM;            // 768*3072

    // 0) conversions (one kernel)
    cvt_all<<<E2 / 1024, 256, 0, stream>>>(x, W_in, W_out, Ax, Bw, Bo);

    // 1) xz = x @ W_in^T : 32 M-tiles x 37 N-tiles = 1184 blocks, col-major slab
    gemm_f16_split<128, 128, 64, 64, 32, true><<<1184, 256, 0, stream>>>(
        Ax, Bw, xz, LSEQ, NCOLS, DIM, NCOLS, WDESCALE);

    // 2) chunked scan
    scan1_kernel<<<dim3(DINNER / 256, NCH), 256, 0, stream>>>(
        xz, W_conv, A_log, ap, he);
    scan2_kernel<<<(DINNER * DSTATE) / 256, 256, 0, stream>>>(ap, he, hi);
    scan3_kernel<<<dim3(DINNER / 256, NCH), 256, 0, stream>>>(
        xz, W_conv, A_log, hi, Dp, Ay);

    // 3) out = yf @ W_out^T : 64 M-tiles x 12 N-tiles = 768 blocks, row-major slab
    gemm_f16_split<64, 64, 32, 32, 12, false><<<768, 256, 0, stream>>>(
        Ay, Bo, out, LSEQ, DIM, DINNER, DIM, WDESCALE);
}

// Round 5
// 265.105 us; speedup vs baseline: 3.1307x; 1.0940x over previous
//
#include <hip/hip_runtime.h>
#include <hip/hip_bf16.h>
#include <math.h>

// Problem constants
#define LSEQ   4096
#define DIM    768
#define DINNER 1536
#define DSTATE 16
#define NCOLS  4640          // 3*DINNER + 2*DSTATE
#define NCH    128           // scan chunks
#define CLEN   32            // steps per chunk
#define NPAD   4736          // W_in rows padded to 37*128

typedef _Float16 f16;
typedef __attribute__((ext_vector_type(8))) _Float16 f16x8;
typedef __attribute__((ext_vector_type(4))) float f32x4;

// W_out pre-scale (exact power of two): keeps W_lo in fp16 normal range.
#define WSCALE   64.0f
#define WDESCALE 0.015625f

// async global(16B/lane) -> LDS staging
__device__ __forceinline__ void gld_lds16(void* lds_dst, const void* gsrc) {
    __builtin_amdgcn_global_load_lds(
        (__attribute__((address_space(1))) void*)(gsrc),
        (__attribute__((address_space(3))) void*)(lds_dst), 16, 0, 0);
}

// ---------------------------------------------------------------------------
// fp16 MFMA GEMM:  C[M,N](fp32) = cscale * A[M,K](f16) * B[N,K]^T
// SPLIT: B rows = [hi(0..K) | lo(0..K)], ldb=2K, both planes -> same acc
//        (W pre-scaled by 64, descaled by cscale in epilogue).
// ZMODE: blocks with n0 in [1536,3072) write f16 to Z[row*1536 + col-1536]
//        (the silu-gate columns), all other blocks write f32 to C.
// 256 threads = 4 waves; wave tile WM x WN; (BM/WM)*(BN/WN) == 4.
// XCD swizzle: idx=(b&7)*P+(b>>3);
//   COLM=true : m0=(idx%NTB)*BM (NTB = M-tiles; B-locality per XCD)
//   COLM=false: n0=(idx%NTB)*BN (NTB = N-tiles; A-locality per XCD)
// ---------------------------------------------------------------------------
template<int BM, int BN, int WM, int WN, int NTB, bool COLM, bool SPLIT, bool ZMODE>
__global__ __launch_bounds__(256) void gemm_f16(const f16* __restrict__ A,
                                                const f16* __restrict__ B,
                                                float* __restrict__ C,
                                                f16* __restrict__ Z,
                                                int M, int N, int K, int ldc,
                                                float cscale) {
    constexpr int MI  = WM / 16;
    constexpr int NI  = WN / 16;
    constexpr int NWN = BN / WN;
    constexpr int nA  = BM / 16;
    constexpr int nB  = BN / 16;
    constexpr int NPL = SPLIT ? 2 : 1;
    constexpr int NT  = nA + NPL * nB;

    __shared__ __align__(16) f16 As[BM * 32];
    __shared__ __align__(16) f16 Bs[NPL * BN * 32];

    const int P   = gridDim.x >> 3;
    const int idx = (blockIdx.x & 7) * P + (blockIdx.x >> 3);
    const int m0  = (COLM ? (idx % NTB) : (idx / NTB)) * BM;
    const int n0  = (COLM ? (idx / NTB) : (idx % NTB)) * BN;

    const int tid  = threadIdx.x;
    const int w    = tid >> 6;
    const int lane = tid & 63;
    const int wr   = w / NWN;
    const int wc   = w % NWN;
    const int m    = lane & 15;
    const int q    = lane >> 4;
    const int rsub = lane >> 2;               // staging row within 16-row group
    const int bsel = lane & 3;                // staging 16B-block index
    const int ldb  = NPL * K;

    f32x4 acc[MI][NI];
#pragma unroll
    for (int i = 0; i < MI; i++)
#pragma unroll
        for (int j = 0; j < NI; j++) acc[i][j] = (f32x4){0.f, 0.f, 0.f, 0.f};

    const int fragoff = ((q ^ (m & 3)) << 3);

    for (int k0 = 0; k0 < K; k0 += 32) {
#pragma unroll
        for (int t = w; t < NT; t += 4) {
            const f16* g; f16* lb; int rl;
            if (t < nA) {
                rl = t * 16 + rsub;
                g  = A + (size_t)(m0 + rl) * K + k0 + (bsel ^ (rl & 3)) * 8;
                lb = As + t * 16 * 32;
            } else if (t < nA + nB) {
                int tt = t - nA; rl = tt * 16 + rsub;
                g  = B + (size_t)(n0 + rl) * ldb + k0 + (bsel ^ (rl & 3)) * 8;
                lb = Bs + tt * 16 * 32;
            } else {
                int tt = t - nA - nB; rl = tt * 16 + rsub;
                g  = B + (size_t)(n0 + rl) * ldb + K + k0 + (bsel ^ (rl & 3)) * 8;
                lb = Bs + (nB + tt) * 16 * 32;
            }
            gld_lds16(lb, g);
        }
        __syncthreads();   // drains vmcnt(0): staging complete

        f16x8 af[MI], bh[NI];
#pragma unroll
        for (int i = 0; i < MI; i++)
            af[i] = *(const f16x8*)&As[(wr * WM + i * 16 + m) * 32 + fragoff];
#pragma unroll
        for (int j = 0; j < NI; j++)
            bh[j] = *(const f16x8*)&Bs[(wc * WN + j * 16 + m) * 32 + fragoff];
#pragma unroll
        for (int i = 0; i < MI; i++)
#pragma unroll
            for (int j = 0; j < NI; j++)
                acc[i][j] = __builtin_amdgcn_mfma_f32_16x16x32_f16(af[i], bh[j], acc[i][j], 0, 0, 0);
        if (SPLIT) {
            f16x8 bl[NI];
#pragma unroll
            for (int j = 0; j < NI; j++)
                bl[j] = *(const f16x8*)&Bs[BN * 32 + (wc * WN + j * 16 + m) * 32 + fragoff];
#pragma unroll
            for (int i = 0; i < MI; i++)
#pragma unroll
                for (int j = 0; j < NI; j++)
                    acc[i][j] = __builtin_amdgcn_mfma_f32_16x16x32_f16(af[i], bl[j], acc[i][j], 0, 0, 0);
        }
        __syncthreads();
    }

    // epilogue: C/D layout col=lane&15, row=q*4+reg
    if (ZMODE && n0 >= DINNER && n0 < 2 * DINNER) {
        // silu-gate columns -> compact f16 Z[row][col-1536]
#pragma unroll
        for (int i = 0; i < MI; i++) {
#pragma unroll
            for (int j = 0; j < NI; j++) {
                const int col = n0 - DINNER + wc * WN + j * 16 + m;
                const int rowb = m0 + wr * WM + i * 16 + q * 4;
#pragma unroll
                for (int r = 0; r < 4; r++)
                    Z[(size_t)(rowb + r) * DINNER + col] = (f16)acc[i][j][r];
            }
        }
        return;
    }
#pragma unroll
    for (int i = 0; i < MI; i++) {
#pragma unroll
        for (int j = 0; j < NI; j++) {
            const int col = n0 + wc * WN + j * 16 + m;
            if (col >= N) continue;
            const int rowb = m0 + wr * WM + i * 16 + q * 4;
#pragma unroll
            for (int r = 0; r < 4; r++)
                C[(size_t)(rowb + r) * ldc + col] = acc[i][j][r] * cscale;
        }
    }
}

// ---------------------------------------------------------------------------
// merged conversions: Ax (f16 x), Bw (f16 W_in single-plane, padded),
//                     Bo (W_out split hi|lo, pre-scaled by 64)
// ---------------------------------------------------------------------------
#define E0 (LSEQ * DIM)            // 3,145,728
#define E1 (E0 + NPAD * DIM)       // + 3,637,248
#define E2 (E1 + DIM * DINNER)     // + 1,179,648

__global__ __launch_bounds__(256) void cvt_all(const float* __restrict__ x,
                                               const float* __restrict__ Wi,
                                               const float* __restrict__ Wo,
                                               f16* __restrict__ Ax,
                                               f16* __restrict__ Bw,
                                               f16* __restrict__ Bo) {
    int i = (blockIdx.x * 256 + threadIdx.x) * 4;
    if (i < E0) {
        float4 v = *(const float4*)(x + i);
        Ax[i] = (f16)v.x; Ax[i+1] = (f16)v.y; Ax[i+2] = (f16)v.z; Ax[i+3] = (f16)v.w;
    } else if (i < E1) {
        int e = i - E0;
        int n = e / DIM;
        if (n < NCOLS) {
            float4 v = *(const float4*)(Wi + e);
            Bw[e] = (f16)v.x; Bw[e+1] = (f16)v.y; Bw[e+2] = (f16)v.z; Bw[e+3] = (f16)v.w;
        } else {
            Bw[e] = (f16)0.f; Bw[e+1] = (f16)0.f; Bw[e+2] = (f16)0.f; Bw[e+3] = (f16)0.f;
        }
    } else if (i < E2) {
        int e = i - E1;
        int n = e / DINNER, k = e - n * DINNER;
        float4 v = *(const float4*)(Wo + e);
        float a[4] = {v.x * WSCALE, v.y * WSCALE, v.z * WSCALE, v.w * WSCALE};
        f16* row = Bo + (size_t)n * (2 * DINNER) + k;
#pragma unroll
        for (int j = 0; j < 4; j++) {
            f16 hi = (f16)a[j];
            row[j] = hi; row[DINNER + j] = (f16)(a[j] - (float)hi);
        }
    }
}

// ---------------------------------------------------------------------------
// scan phase 1: conv+silu+softplus fused; local scan h=0 -> h_end; aprod.
// ---------------------------------------------------------------------------
__global__ __launch_bounds__(256) void scan1_kernel(const float* __restrict__ xz,
                                                    const float* __restrict__ Wc,
                                                    const float* __restrict__ A_log,
                                                    float* __restrict__ aprod,
                                                    float* __restrict__ hend) {
    __shared__ float Bs[CLEN * DSTATE];
    const int d  = blockIdx.x * 256 + threadIdx.x;
    const int c  = blockIdx.y;
    const int l0 = c * CLEN;
    for (int i = threadIdx.x; i < CLEN * DSTATE; i += 256)
        Bs[i] = xz[(size_t)(l0 + (i >> 4)) * NCOLS + 3072 + (i & 15)];
    float Areg[DSTATE];
#pragma unroll
    for (int n = 0; n < DSTATE; n++) Areg[n] = -__expf(A_log[d * DSTATE + n]);
    const float w0 = Wc[d * 3 + 0], w1 = Wc[d * 3 + 1], w2 = Wc[d * 3 + 2];
    float xm = (l0 > 0) ? xz[(size_t)(l0 - 1) * NCOLS + d] : 0.f;
    float x0 = xz[(size_t)l0 * NCOLS + d];
    float ld_xp   = xz[(size_t)(l0 + 1) * NCOLS + d];
    float ld_draw = xz[(size_t)l0 * NCOLS + 3104 + d];
    __syncthreads();

    float h[DSTATE];
#pragma unroll
    for (int n = 0; n < DSTATE; n++) h[n] = 0.f;
    float S = 0.f;

    for (int t = 0; t < CLEN; t++) {
        const int l = l0 + t;
        float xp = ld_xp, draw = ld_draw;
        if (t + 1 < CLEN) {
            ld_xp   = (l + 2 < LSEQ) ? xz[(size_t)(l + 2) * NCOLS + d] : 0.f;
            ld_draw = xz[(size_t)(l + 1) * NCOLS + 3104 + d];
        }
        float v  = xm * w0 + x0 * w1 + xp * w2;
        float xcv = __fdividef(v, 1.f + __expf(-v));
        float dtv = (draw > 20.f) ? draw : __logf(1.f + __expf(draw));
        float u = dtv * xcv;
        S += dtv;
#pragma unroll
        for (int n = 0; n < DSTATE; n++) {
            float e = __expf(dtv * Areg[n]);
            h[n] = e * h[n] + u * Bs[t * DSTATE + n];
        }
        xm = x0; x0 = xp;
    }
#pragma unroll
    for (int n = 0; n < DSTATE; n++) {
        size_t idx = ((size_t)c * DSTATE + n) * DINNER + d;
        aprod[idx] = __expf(S * Areg[n]);
        hend[idx]  = h[n];
    }
}

// ---------------------------------------------------------------------------
// scan phase 2: sequential over NCH chunk summaries, pipelined loads
// ---------------------------------------------------------------------------
__global__ __launch_bounds__(256) void scan2_kernel(const float* __restrict__ aprod,
                                                    const float* __restrict__ hend,
                                                    float* __restrict__ hinit) {
    const int g = blockIdx.x * 256 + threadIdx.x;
    const size_t S = (size_t)DSTATE * DINNER;
    size_t idx = g;
    float a = aprod[idx], e = hend[idx];
    float h = 0.f;
#pragma unroll 4
    for (int c = 0; c < NCH; c++) {
        float ac = a, ec = e;
        if (c + 1 < NCH) { a = aprod[idx + S]; e = hend[idx + S]; }
        hinit[idx] = h;
        h = ac * h + ec;
        idx += S;
    }
}

// ---------------------------------------------------------------------------
// scan phase 3: replay from h_init; z-gate from f16 Zb; emit f16 Ay
// ---------------------------------------------------------------------------
__global__ __launch_bounds__(256) void scan3_kernel(const float* __restrict__ xz,
                                                    const f16* __restrict__ Zb,
                                                    const float* __restrict__ Wc,
                                                    const float* __restrict__ A_log,
                                                    const float* __restrict__ hinit,
                                                    const float* __restrict__ Dp,
                                                    f16* __restrict__ Ay) {
    __shared__ float Bs[CLEN * DSTATE];
    __shared__ float Cs[CLEN * DSTATE];
    const int d  = blockIdx.x * 256 + threadIdx.x;
    const int c  = blockIdx.y;
    const int l0 = c * CLEN;
    for (int i = threadIdx.x; i < CLEN * DSTATE; i += 256) {
        size_t roff = (size_t)(l0 + (i >> 4)) * NCOLS;
        Bs[i] = xz[roff + 3072 + (i & 15)];
        Cs[i] = xz[roff + 3088 + (i & 15)];
    }
    float Areg[DSTATE];
#pragma unroll
    for (int n = 0; n < DSTATE; n++) Areg[n] = -__expf(A_log[d * DSTATE + n]);
    float h[DSTATE];
#pragma unroll
    for (int n = 0; n < DSTATE; n++)
        h[n] = hinit[((size_t)c * DSTATE + n) * DINNER + d];
    const float Dv = Dp[d];
    const float w0 = Wc[d * 3 + 0], w1 = Wc[d * 3 + 1], w2 = Wc[d * 3 + 2];
    float xm = (l0 > 0) ? xz[(size_t)(l0 - 1) * NCOLS + d] : 0.f;
    float x0 = xz[(size_t)l0 * NCOLS + d];
    float ld_xp   = xz[(size_t)(l0 + 1) * NCOLS + d];
    float ld_draw = xz[(size_t)l0 * NCOLS + 3104 + d];
    float ld_z    = (float)Zb[(size_t)l0 * DINNER + d];
    __syncthreads();

    for (int t = 0; t < CLEN; t++) {
        const int l = l0 + t;
        float xp = ld_xp, draw = ld_draw, zv = ld_z;
        if (t + 1 < CLEN) {
            ld_xp   = (l + 2 < LSEQ) ? xz[(size_t)(l + 2) * NCOLS + d] : 0.f;
            ld_draw = xz[(size_t)(l + 1) * NCOLS + 3104 + d];
            ld_z    = (float)Zb[(size_t)(l + 1) * DINNER + d];
        }
        float v  = xm * w0 + x0 * w1 + xp * w2;
        float xcv = __fdividef(v, 1.f + __expf(-v));
        float dtv = (draw > 20.f) ? draw : __logf(1.f + __expf(draw));
        float u = dtv * xcv;
        float y = 0.f;
#pragma unroll
        for (int n = 0; n < DSTATE; n++) {
            float e = __expf(dtv * Areg[n]);
            h[n] = e * h[n] + u * Bs[t * DSTATE + n];
            y += h[n] * Cs[t * DSTATE + n];
        }
        float sz = __fdividef(zv, 1.f + __expf(-zv));
        Ay[(size_t)l * DINNER + d] = (f16)((y + xcv * Dv) * sz);
        xm = x0; x0 = xp;
    }
}

// ---------------------------------------------------------------------------
extern "C" void kernel_launch(void* const* d_in, const int* in_sizes, int n_in,
                              void* d_out, int out_size, void* d_ws, size_t ws_size,
                              hipStream_t stream) {
    const float* x     = (const float*)d_in[0];
    const float* W_in  = (const float*)d_in[1];
    const float* W_conv= (const float*)d_in[2];
    const float* W_out = (const float*)d_in[3];
    const float* A_log = (const float*)d_in[4];
    const float* Dp    = (const float*)d_in[5];
    float* out = (float*)d_out;

    // workspace carve-up (~158 MB)
    float* ws  = (float*)d_ws;
    float* xz  = ws;                                  // 19,005,440 f (z-region unused)
    float* ap  = xz + (size_t)LSEQ * NCOLS;           // 3,145,728
    float* he  = ap + (size_t)NCH * DSTATE * DINNER;  // 3,145,728
    float* hi  = he + (size_t)NCH * DSTATE * DINNER;  // 3,145,728
    f16* Ax = (f16*)(hi + (size_t)NCH * DSTATE * DINNER); // 4096*768
    f16* Ay = Ax + (size_t)LSEQ * DIM;                // 4096*1536
    f16* Bw = Ay + (size_t)LSEQ * DINNER;             // 4736*768
    f16* Bo = Bw + (size_t)NPAD * DIM;                // 768*3072
    f16* Zb = Bo + (size_t)DIM * 2 * DINNER;          // 4096*1536

    // 0) conversions (one kernel)
    cvt_all<<<E2 / 1024, 256, 0, stream>>>(x, W_in, W_out, Ax, Bw, Bo);

    // 1) xz = x @ W_in^T : single-plane f16 W, z-tiles -> f16 Zb.
    //    32 M-tiles x 37 N-tiles = 1184 blocks, col-major XCD slab (B-locality)
    gemm_f16<128, 128, 64, 64, 32, true, false, true><<<1184, 256, 0, stream>>>(
        Ax, Bw, xz, Zb, LSEQ, NCOLS, DIM, NCOLS, 1.0f);

    // 2) chunked scan
    scan1_kernel<<<dim3(DINNER / 256, NCH), 256, 0, stream>>>(
        xz, W_conv, A_log, ap, he);
    scan2_kernel<<<(DINNER * DSTATE) / 256, 256, 0, stream>>>(ap, he, hi);
    scan3_kernel<<<dim3(DINNER / 256, NCH), 256, 0, stream>>>(
        xz, Zb, W_conv, A_log, hi, Dp, Ay);

    // 3) out = yf @ W_out^T : split (hi+lo) W, 64 M-tiles x 12 N-tiles = 768 blocks
    gemm_f16<64, 64, 32, 32, 12, false, true, false><<<768, 256, 0, stream>>>(
        Ay, Bo, out, nullptr, LSEQ, DIM, DINNER, DIM, WDESCALE);
}

// Round 6
// 246.647 us; speedup vs baseline: 3.3650x; 1.0748x over previous
//
#include <hip/hip_runtime.h>
#include <hip/hip_bf16.h>
#include <math.h>

// Problem constants
#define LSEQ   4096
#define DIM    768
#define DINNER 1536
#define DSTATE 16
#define NCOLS  4640          // 3*DINNER + 2*DSTATE
#define NCH    128           // scan chunks
#define CLEN   32            // steps per chunk
#define NPAD   4736          // W_in rows padded to 37*128
#define DXW    1568          // compact f32 width: B(16) C(16) delta(1536)

typedef _Float16 f16;
typedef __attribute__((ext_vector_type(8))) _Float16 f16x8;
typedef __attribute__((ext_vector_type(4))) float f32x4;

// async global(16B/lane) -> LDS staging
__device__ __forceinline__ void gld_lds16(void* lds_dst, const void* gsrc) {
    __builtin_amdgcn_global_load_lds(
        (__attribute__((address_space(1))) void*)(gsrc),
        (__attribute__((address_space(3))) void*)(lds_dst), 16, 0, 0);
}

// ---------------------------------------------------------------------------
// fp16 MFMA GEMM, BK=64:  C = A[M,K](f16) * B[N,K]^T(f16), fp32 accumulate.
// LDS tile rows are 128B (8 x 16B blocks); global block b of row r lands in
// LDS block b^(r&7) (lane L of each 1KB staging instr fetches global block
// (L&7)^(row&7)); fragment reads then hit 2-way-free bank pattern.
// ZMODE (GEMM1): cols [0,1536) -> f16 Xb, [1536,3072) -> f16 Zb,
//                [3072,4640) -> f32 C at col-3072 (ldc=DXW).
// XCD swizzle: idx=(b&7)*P+(b>>3);
//   COLM=true : m0=(idx%NTB)*BM (B-locality per XCD), else n0=(idx%NTB)*BN.
// ---------------------------------------------------------------------------
template<int BM, int BN, int WM, int WN, int NTB, bool COLM, bool ZMODE>
__global__ __launch_bounds__(256) void gemm_f16(const f16* __restrict__ A,
                                                const f16* __restrict__ B,
                                                float* __restrict__ C,
                                                f16* __restrict__ Xb,
                                                f16* __restrict__ Zb,
                                                int M, int N, int K, int ldc) {
    constexpr int MI  = WM / 16;
    constexpr int NI  = WN / 16;
    constexpr int NWN = BN / WN;
    constexpr int RT  = BM + BN;          // rows per k-tile
    constexpr int NS  = RT / 8;           // 1KB staging instructions per k-step

    __shared__ __align__(16) f16 S[RT * 64];
    f16* As = S;
    f16* Bs = S + BM * 64;

    const int P   = gridDim.x >> 3;
    const int idx = (blockIdx.x & 7) * P + (blockIdx.x >> 3);
    const int m0  = (COLM ? (idx % NTB) : (idx / NTB)) * BM;
    const int n0  = (COLM ? (idx / NTB) : (idx % NTB)) * BN;

    const int tid  = threadIdx.x;
    const int w    = tid >> 6;
    const int lane = tid & 63;
    const int wr   = w / NWN;
    const int wc   = w % NWN;
    const int m    = lane & 15;           // fragment row(A)/col(B)
    const int q    = lane >> 4;           // quad
    const int rl8  = lane >> 3;           // staging: row within 8-row group
    const int bsel = lane & 7;            // staging: 16B-block index

    f32x4 acc[MI][NI];
#pragma unroll
    for (int i = 0; i < MI; i++)
#pragma unroll
        for (int j = 0; j < NI; j++) acc[i][j] = (f32x4){0.f, 0.f, 0.f, 0.f};

    for (int k0 = 0; k0 < K; k0 += 64) {
#pragma unroll
        for (int t = w; t < NS; t += 4) {
            const int rl  = t * 8 + rl8;
            const int blk = bsel ^ (rl & 7);
            const f16* g = (rl < BM)
                ? A + (size_t)(m0 + rl) * K + k0 + blk * 8
                : B + (size_t)(n0 + rl - BM) * K + k0 + blk * 8;
            gld_lds16(S + t * 8 * 64, g);
        }
        __syncthreads();   // drains vmcnt(0): staging complete

#pragma unroll
        for (int kk = 0; kk < 2; kk++) {
            const int fo = (((q + 4 * kk) ^ (m & 7)) << 3);
            f16x8 af[MI], bh[NI];
#pragma unroll
            for (int i = 0; i < MI; i++)
                af[i] = *(const f16x8*)&As[(wr * WM + i * 16 + m) * 64 + fo];
#pragma unroll
            for (int j = 0; j < NI; j++)
                bh[j] = *(const f16x8*)&Bs[(wc * WN + j * 16 + m) * 64 + fo];
#pragma unroll
            for (int i = 0; i < MI; i++)
#pragma unroll
                for (int j = 0; j < NI; j++)
                    acc[i][j] = __builtin_amdgcn_mfma_f32_16x16x32_f16(
                        af[i], bh[j], acc[i][j], 0, 0, 0);
        }
        __syncthreads();
    }

    // epilogue: C/D layout col=lane&15, row=q*4+reg
    if (ZMODE && n0 < DINNER) {            // x_inner cols -> f16 Xb
#pragma unroll
        for (int i = 0; i < MI; i++)
#pragma unroll
            for (int j = 0; j < NI; j++) {
                const int col  = n0 + wc * WN + j * 16 + m;
                const int rowb = m0 + wr * WM + i * 16 + q * 4;
#pragma unroll
                for (int r = 0; r < 4; r++)
                    Xb[(size_t)(rowb + r) * DINNER + col] = (f16)acc[i][j][r];
            }
        return;
    }
    if (ZMODE && n0 < 2 * DINNER) {        // z cols -> f16 Zb
#pragma unroll
        for (int i = 0; i < MI; i++)
#pragma unroll
            for (int j = 0; j < NI; j++) {
                const int col  = n0 - DINNER + wc * WN + j * 16 + m;
                const int rowb = m0 + wr * WM + i * 16 + q * 4;
#pragma unroll
                for (int r = 0; r < 4; r++)
                    Zb[(size_t)(rowb + r) * DINNER + col] = (f16)acc[i][j][r];
            }
        return;
    }
#pragma unroll
    for (int i = 0; i < MI; i++)
#pragma unroll
        for (int j = 0; j < NI; j++) {
            const int col  = (ZMODE ? n0 - 2 * DINNER : n0) + wc * WN + j * 16 + m;
            const int lim  = ZMODE ? DXW : N;
            if (col >= lim) continue;
            const int rowb = m0 + wr * WM + i * 16 + q * 4;
#pragma unroll
            for (int r = 0; r < 4; r++)
                C[(size_t)(rowb + r) * ldc + col] = acc[i][j][r];
        }
}

// ---------------------------------------------------------------------------
// merged conversions: Ax (f16 x), Bw (f16 W_in, zero-padded), Bo (f16 W_out)
// ---------------------------------------------------------------------------
#define E0 (LSEQ * DIM)            // 3,145,728
#define E1 (E0 + NPAD * DIM)       // + 3,637,248
#define E2 (E1 + DIM * DINNER)     // + 1,179,648

__global__ __launch_bounds__(256) void cvt_all(const float* __restrict__ x,
                                               const float* __restrict__ Wi,
                                               const float* __restrict__ Wo,
                                               f16* __restrict__ Ax,
                                               f16* __restrict__ Bw,
                                               f16* __restrict__ Bo) {
    int i = (blockIdx.x * 256 + threadIdx.x) * 4;
    if (i < E0) {
        float4 v = *(const float4*)(x + i);
        Ax[i] = (f16)v.x; Ax[i+1] = (f16)v.y; Ax[i+2] = (f16)v.z; Ax[i+3] = (f16)v.w;
    } else if (i < E1) {
        int e = i - E0;
        int n = e / DIM;
        if (n < NCOLS) {
            float4 v = *(const float4*)(Wi + e);
            Bw[e] = (f16)v.x; Bw[e+1] = (f16)v.y; Bw[e+2] = (f16)v.z; Bw[e+3] = (f16)v.w;
        } else {
            Bw[e] = (f16)0.f; Bw[e+1] = (f16)0.f; Bw[e+2] = (f16)0.f; Bw[e+3] = (f16)0.f;
        }
    } else if (i < E2) {
        int e = i - E1;
        float4 v = *(const float4*)(Wo + e);
        Bo[e] = (f16)v.x; Bo[e+1] = (f16)v.y; Bo[e+2] = (f16)v.z; Bo[e+3] = (f16)v.w;
    }
}

// ---------------------------------------------------------------------------
// scan phase 1: conv+silu+softplus fused; local scan h=0 -> h_end; aprod.
// x from f16 Xb; delta/B from f32 Dxz (width DXW: B|C|delta).
// ---------------------------------------------------------------------------
__global__ __launch_bounds__(256) void scan1_kernel(const float* __restrict__ Dxz,
                                                    const f16* __restrict__ Xb,
                                                    const float* __restrict__ Wc,
                                                    const float* __restrict__ A_log,
                                                    float* __restrict__ aprod,
                                                    float* __restrict__ hend) {
    __shared__ float Bs[CLEN * DSTATE];
    const int d  = blockIdx.x * 256 + threadIdx.x;
    const int c  = blockIdx.y;
    const int l0 = c * CLEN;
    for (int i = threadIdx.x; i < CLEN * DSTATE; i += 256)
        Bs[i] = Dxz[(size_t)(l0 + (i >> 4)) * DXW + (i & 15)];
    float Areg[DSTATE];
#pragma unroll
    for (int n = 0; n < DSTATE; n++) Areg[n] = -__expf(A_log[d * DSTATE + n]);
    const float w0 = Wc[d * 3 + 0], w1 = Wc[d * 3 + 1], w2 = Wc[d * 3 + 2];
    float xm = (l0 > 0) ? (float)Xb[(size_t)(l0 - 1) * DINNER + d] : 0.f;
    float x0 = (float)Xb[(size_t)l0 * DINNER + d];
    float ld_xp   = (float)Xb[(size_t)(l0 + 1) * DINNER + d];
    float ld_draw = Dxz[(size_t)l0 * DXW + 32 + d];
    __syncthreads();

    float h[DSTATE];
#pragma unroll
    for (int n = 0; n < DSTATE; n++) h[n] = 0.f;
    float S = 0.f;

    for (int t = 0; t < CLEN; t++) {
        const int l = l0 + t;
        float xp = ld_xp, draw = ld_draw;
        if (t + 1 < CLEN) {
            ld_xp   = (l + 2 < LSEQ) ? (float)Xb[(size_t)(l + 2) * DINNER + d] : 0.f;
            ld_draw = Dxz[(size_t)(l + 1) * DXW + 32 + d];
        }
        float v  = xm * w0 + x0 * w1 + xp * w2;
        float xcv = __fdividef(v, 1.f + __expf(-v));
        float dtv = (draw > 20.f) ? draw : __logf(1.f + __expf(draw));
        float u = dtv * xcv;
        S += dtv;
#pragma unroll
        for (int n = 0; n < DSTATE; n++) {
            float e = __expf(dtv * Areg[n]);
            h[n] = e * h[n] + u * Bs[t * DSTATE + n];
        }
        xm = x0; x0 = xp;
    }
#pragma unroll
    for (int n = 0; n < DSTATE; n++) {
        size_t idx = ((size_t)c * DSTATE + n) * DINNER + d;
        aprod[idx] = __expf(S * Areg[n]);
        hend[idx]  = h[n];
    }
}

// ---------------------------------------------------------------------------
// scan phase 2: sequential over NCH chunk summaries, pipelined loads
// ---------------------------------------------------------------------------
__global__ __launch_bounds__(256) void scan2_kernel(const float* __restrict__ aprod,
                                                    const float* __restrict__ hend,
                                                    float* __restrict__ hinit) {
    const int g = blockIdx.x * 256 + threadIdx.x;
    const size_t S = (size_t)DSTATE * DINNER;
    size_t idx = g;
    float a = aprod[idx], e = hend[idx];
    float h = 0.f;
#pragma unroll 4
    for (int c = 0; c < NCH; c++) {
        float ac = a, ec = e;
        if (c + 1 < NCH) { a = aprod[idx + S]; e = hend[idx + S]; }
        hinit[idx] = h;
        h = ac * h + ec;
        idx += S;
    }
}

// ---------------------------------------------------------------------------
// scan phase 3: replay from h_init; z-gate from f16 Zb; emit f16 Ay
// ---------------------------------------------------------------------------
__global__ __launch_bounds__(256) void scan3_kernel(const float* __restrict__ Dxz,
                                                    const f16* __restrict__ Xb,
                                                    const f16* __restrict__ Zb,
                                                    const float* __restrict__ Wc,
                                                    const float* __restrict__ A_log,
                                                    const float* __restrict__ hinit,
                                                    const float* __restrict__ Dp,
                                                    f16* __restrict__ Ay) {
    __shared__ float Bs[CLEN * DSTATE];
    __shared__ float Cs[CLEN * DSTATE];
    const int d  = blockIdx.x * 256 + threadIdx.x;
    const int c  = blockIdx.y;
    const int l0 = c * CLEN;
    for (int i = threadIdx.x; i < CLEN * DSTATE; i += 256) {
        size_t roff = (size_t)(l0 + (i >> 4)) * DXW;
        Bs[i] = Dxz[roff + (i & 15)];
        Cs[i] = Dxz[roff + 16 + (i & 15)];
    }
    float Areg[DSTATE];
#pragma unroll
    for (int n = 0; n < DSTATE; n++) Areg[n] = -__expf(A_log[d * DSTATE + n]);
    float h[DSTATE];
#pragma unroll
    for (int n = 0; n < DSTATE; n++)
        h[n] = hinit[((size_t)c * DSTATE + n) * DINNER + d];
    const float Dv = Dp[d];
    const float w0 = Wc[d * 3 + 0], w1 = Wc[d * 3 + 1], w2 = Wc[d * 3 + 2];
    float xm = (l0 > 0) ? (float)Xb[(size_t)(l0 - 1) * DINNER + d] : 0.f;
    float x0 = (float)Xb[(size_t)l0 * DINNER + d];
    float ld_xp   = (float)Xb[(size_t)(l0 + 1) * DINNER + d];
    float ld_draw = Dxz[(size_t)l0 * DXW + 32 + d];
    float ld_z    = (float)Zb[(size_t)l0 * DINNER + d];
    __syncthreads();

    for (int t = 0; t < CLEN; t++) {
        const int l = l0 + t;
        float xp = ld_xp, draw = ld_draw, zv = ld_z;
        if (t + 1 < CLEN) {
            ld_xp   = (l + 2 < LSEQ) ? (float)Xb[(size_t)(l + 2) * DINNER + d] : 0.f;
            ld_draw = Dxz[(size_t)(l + 1) * DXW + 32 + d];
            ld_z    = (float)Zb[(size_t)(l + 1) * DINNER + d];
        }
        float v  = xm * w0 + x0 * w1 + xp * w2;
        float xcv = __fdividef(v, 1.f + __expf(-v));
        float dtv = (draw > 20.f) ? draw : __logf(1.f + __expf(draw));
        float u = dtv * xcv;
        float y = 0.f;
#pragma unroll
        for (int n = 0; n < DSTATE; n++) {
            float e = __expf(dtv * Areg[n]);
            h[n] = e * h[n] + u * Bs[t * DSTATE + n];
            y += h[n] * Cs[t * DSTATE + n];
        }
        float sz = __fdividef(zv, 1.f + __expf(-zv));
        Ay[(size_t)l * DINNER + d] = (f16)((y + xcv * Dv) * sz);
        xm = x0; x0 = xp;
    }
}

// ---------------------------------------------------------------------------
extern "C" void kernel_launch(void* const* d_in, const int* in_sizes, int n_in,
                              void* d_out, int out_size, void* d_ws, size_t ws_size,
                              hipStream_t stream) {
    const float* x     = (const float*)d_in[0];
    const float* W_in  = (const float*)d_in[1];
    const float* W_conv= (const float*)d_in[2];
    const float* W_out = (const float*)d_in[3];
    const float* A_log = (const float*)d_in[4];
    const float* Dp    = (const float*)d_in[5];
    float* out = (float*)d_out;

    // workspace carve-up (~117 MB)
    float* ws  = (float*)d_ws;
    float* Dxz = ws;                                  // 4096*1568 f32
    float* ap  = Dxz + (size_t)LSEQ * DXW;            // 3,145,728
    float* he  = ap + (size_t)NCH * DSTATE * DINNER;  // 3,145,728
    float* hi  = he + (size_t)NCH * DSTATE * DINNER;  // 3,145,728
    f16* Ax = (f16*)(hi + (size_t)NCH * DSTATE * DINNER); // 4096*768
    f16* Ay = Ax + (size_t)LSEQ * DIM;                // 4096*1536
    f16* Bw = Ay + (size_t)LSEQ * DINNER;             // 4736*768
    f16* Bo = Bw + (size_t)NPAD * DIM;                // 768*1536
    f16* Zb = Bo + (size_t)DIM * DINNER;              // 4096*1536
    f16* Xb = Zb + (size_t)LSEQ * DINNER;             // 4096*1536

    // 0) conversions (one kernel)
    cvt_all<<<E2 / 1024, 256, 0, stream>>>(x, W_in, W_out, Ax, Bw, Bo);

    // 1) xz = x @ W_in^T : BK=64, f16 W; x_inner->Xb, z->Zb, B|C|delta->Dxz.
    //    32 M-tiles x 37 N-tiles = 1184 blocks, col-major XCD slab (B-locality)
    gemm_f16<128, 128, 64, 64, 32, true, true><<<1184, 256, 0, stream>>>(
        Ax, Bw, Dxz, Xb, Zb, LSEQ, NCOLS, DIM, DXW);

    // 2) chunked scan
    scan1_kernel<<<dim3(DINNER / 256, NCH), 256, 0, stream>>>(
        Dxz, Xb, W_conv, A_log, ap, he);
    scan2_kernel<<<(DINNER * DSTATE) / 256, 256, 0, stream>>>(ap, he, hi);
    scan3_kernel<<<dim3(DINNER / 256, NCH), 256, 0, stream>>>(
        Dxz, Xb, Zb, W_conv, A_log, hi, Dp, Ay);

    // 3) out = yf @ W_out^T : BK=64, single-plane f16 W_out.
    //    64 M-tiles x 12 N-tiles = 768 blocks, row-major XCD slab (A-locality)
    gemm_f16<64, 64, 32, 32, 12, false, false><<<768, 256, 0, stream>>>(
        Ay, Bo, out, nullptr, nullptr, LSEQ, DIM, DINNER, DIM);
}